// Round 18
// baseline (345.678 us; speedup 1.0000x reference)
//
#include <hip/hip_runtime.h>
#include <cmath>

// GCN: 3 x (dense GEMM <-> pull-SpMM) + fused log_softmax.
// Build: atomic-free two-level counting partition (bucket = dst>>6) ->
// within-bucket counting sort (sort2) -> compact per-node CSR with 4-byte
// records (src 17b | ev 15b fixed-point). gemm1 = MFMA 16x16x32 bf16.
// All pull tables bf16 (3.2MB -> L2-resident). XCD-aware chunk swizzle in
// p3 (write-side line merge in per-XCD L2). p2b folded into p2a.
// Round-18: gemm23 fused into pull2's epilogue -- after the cross-lane
// reduce each wave holds a full a2 row; 16 shuffles broadcast it, lane j
// computes h[j]=leaky(b2[j]+sum a*W2), 64-lane butterfly reduces the 16
// outputs. Deletes the gemm23_k launch and the 12.8MB a2 roundtrip.
// Pulls: wave-per-node, 16 groups x 4 lanes x uint2(4xbf16). No global
// fp32 atomics. Algebra: spmm(A, h@W) == spmm(A, h)@W -> aggregate in 16.
// Layer-1 activation recomputed inside layer-2's gather.

#define BD 64                            // dsts per bucket
#define NBKT 1563                        // ceil(100000/64)
#define NBLK 1024                        // partition blocks (8 XCDs x 128)
#define SORT_CAP 3072                    // max bucket edges staged in LDS

typedef __attribute__((ext_vector_type(8))) short bf16x8;
typedef __attribute__((ext_vector_type(4))) float f32x4;

__device__ __forceinline__ short to_bf16(float f) {
    unsigned u = __float_as_uint(f);
    u += 0x8000u;                         // round-half-up
    return (short)(u >> 16);
}
__device__ __forceinline__ unsigned pack2bf(float a, float b) {
    return (unsigned)(unsigned short)to_bf16(a) |
           ((unsigned)(unsigned short)to_bf16(b) << 16);
}
__device__ __forceinline__ float bf_lo(unsigned v) { return __uint_as_float(v << 16); }
__device__ __forceinline__ float bf_hi(unsigned v) { return __uint_as_float(v & 0xFFFF0000u); }

// ---------------- fused: gemm1 MFMA (x@W1 -> t1 bf16) + bucket hist -------
__global__ __launch_bounds__(256) void p1g_k(const float* __restrict__ x,
                                             const float* __restrict__ W1,
                                             unsigned short* __restrict__ t1,
                                             const int* __restrict__ dst,
                                             int* __restrict__ C,
                                             int* __restrict__ done,
                                             int N, int E, int NB_gemm) {
    if (blockIdx.x == 0 && threadIdx.x == 0) *done = 0;   // for p2a tail
    __shared__ __align__(16) unsigned short wlds[8192];  // 16 KB (union w/ hist)
    if ((int)blockIdx.x < NB_gemm) {
        // --- stage W1 as bf16 B-fragments: [kt][kg][col][j] (j contiguous) ---
        {
            int t = threadIdx.x;
            int kt = t >> 4, col = t & 15;
#pragma unroll
            for (int j = 0; j < 32; ++j) {
                int k = kt * 32 + j;
                float v = W1[(size_t)k * 16 + col];
                wlds[(((kt * 4 + (j >> 3)) * 16 + col) << 3) + (j & 7)] =
                    (unsigned short)to_bf16(v);
            }
        }
        __syncthreads();
        int wid = (blockIdx.x * 256 + (int)threadIdx.x) >> 6;  // global wave id
        int ntiles = (N + 15) >> 4;
        if (wid >= ntiles) return;
        int lane = threadIdx.x & 63;
        int m = lane & 15, kg = lane >> 4;
        int r = wid * 16 + m;
        int rc = r < N ? r : N - 1;                      // clamp (no OOB addr)
        const float4* Xv = reinterpret_cast<const float4*>(x + (size_t)rc * 512);
        f32x4 acc = {0.f, 0.f, 0.f, 0.f};
#pragma unroll
        for (int kt = 0; kt < 16; ++kt) {
            float4 xa = Xv[kt * 8 + kg * 2];
            float4 xb = Xv[kt * 8 + kg * 2 + 1];
            bf16x8 a;
            a[0] = to_bf16(xa.x); a[1] = to_bf16(xa.y);
            a[2] = to_bf16(xa.z); a[3] = to_bf16(xa.w);
            a[4] = to_bf16(xb.x); a[5] = to_bf16(xb.y);
            a[6] = to_bf16(xb.z); a[7] = to_bf16(xb.w);
            bf16x8 b = *reinterpret_cast<const bf16x8*>(
                &wlds[((kt * 4 + kg) * 16 + m) << 3]);
            acc = __builtin_amdgcn_mfma_f32_16x16x32_bf16(a, b, acc, 0, 0, 0);
        }
        // D: col = lane&15 (=m), row = kg*4 + i
#pragma unroll
        for (int i = 0; i < 4; ++i) {
            int ro = wid * 16 + kg * 4 + i;
            if (ro < N) t1[(size_t)ro * 16 + m] = (unsigned short)to_bf16(acc[i]);
        }
        return;
    }
    int* h = (int*)wlds;
    int k = (int)blockIdx.x - NB_gemm;
    for (int i = threadIdx.x; i < NBKT; i += 256) h[i] = 0;
    __syncthreads();
    int epb = (E + NBLK - 1) / NBLK;
    int lo = k * epb, hi = min(lo + epb, E);
    for (int e = lo + (int)threadIdx.x; e < hi; e += 256)
        atomicAdd(&h[dst[e] >> 6], 1);
    __syncthreads();
    for (int i = threadIdx.x; i < NBKT; i += 256)
        C[(size_t)k * NBKT + i] = h[i];
}

// ---------------- P2a (+fused P2b via done-counter last block) ------------
__global__ __launch_bounds__(256) void p2a(int* __restrict__ C,
                                           int* __restrict__ btot,
                                           int* __restrict__ bbase,
                                           int* __restrict__ done) {
    __shared__ int s[16][17];
    __shared__ int ps[256];
    __shared__ int isLast;
    int bs = threadIdx.x & 15, ki = threadIdx.x >> 4;
    int b = blockIdx.x * 16 + bs;
    bool ok = b < NBKT;
    int sum = 0;
    if (ok) {
        for (int j = 0; j < 64; ++j)
            sum += C[(size_t)(ki * 64 + j) * NBKT + b];
    }
    s[ki][bs] = sum;
    __syncthreads();
    int base = 0;
    for (int j = 0; j < ki; ++j) base += s[j][bs];
    if (ok) {
        if (ki == 15) btot[b] = base + sum;
        int run = base;
        for (int j = 0; j < 64; ++j) {
            size_t idx = (size_t)(ki * 64 + j) * NBKT + b;
            int v = C[idx];
            C[idx] = run;                 // exclusive offset
            run += v;
        }
    }
    // ---- last finishing block performs the bucket-base scan (old p2b) ----
    __syncthreads();
    if (threadIdx.x == 0) {
        __threadfence();
        isLast = (atomicAdd(done, 1) == (int)gridDim.x - 1);
    }
    __syncthreads();
    if (!isLast) return;
    int loc[8], ssum = 0;
    int base2 = (int)threadIdx.x * 8;     // 2048 >= NBKT+1
#pragma unroll
    for (int j = 0; j < 8; ++j) {
        int i = base2 + j;
        int v = (i < NBKT) ? btot[i] : 0;
        loc[j] = ssum; ssum += v;
    }
    ps[threadIdx.x] = ssum;
    __syncthreads();
    for (int st = 1; st < 256; st <<= 1) {
        int tv = (threadIdx.x >= (unsigned)st) ? ps[threadIdx.x - st] : 0;
        __syncthreads();
        ps[threadIdx.x] += tv;
        __syncthreads();
    }
    int prev = ps[threadIdx.x] - ssum;
#pragma unroll
    for (int j = 0; j < 8; ++j) {
        int i = base2 + j;
        if (i <= NBKT) bbase[i] = prev + loc[j];
    }
}

// ---------------- P3: scatter bucket-sorted records (LDS cursors) ---------
__global__ __launch_bounds__(256) void p3_place(const int* __restrict__ src,
                                                const int* __restrict__ dst,
                                                const float* __restrict__ ev,
                                                const int* __restrict__ C,
                                                const int* __restrict__ bbase,
                                                int2* __restrict__ recA, int E) {
    __shared__ int cur[NBKT];
    int bid = (int)blockIdx.x;
    int k = ((bid & 7) << 7) | (bid >> 3);   // (bid%8)*128 + bid/8
    for (int i = threadIdx.x; i < NBKT; i += 256)
        cur[i] = bbase[i] + C[(size_t)k * NBKT + i];
    __syncthreads();
    int epb = (E + NBLK - 1) / NBLK;
    int lo = k * epb, hi = min(lo + epb, E);
    for (int e = lo + (int)threadIdx.x; e < hi; e += 256) {
        int d = dst[e];
        int p = atomicAdd(&cur[d >> 6], 1);   // LDS ds_add_rtn
        recA[p] = make_int2(src[e] | ((d & 63) << 17), __float_as_int(ev[e]));
    }
}

// ---------------- sort2: within-bucket counting sort -> 4B-record CSR -----
__device__ __forceinline__ int pack_rec(int srcbits, float evf) {
    int q = (int)(evf * 32768.f + 0.5f);
    q = q > 32767 ? 32767 : q;
    return (srcbits << 15) | q;
}

__global__ __launch_bounds__(256) void sort2_k(const int* __restrict__ bbase,
                                               const int2* __restrict__ recA,
                                               int* __restrict__ recB,
                                               int* __restrict__ off,
                                               int N, int E) {
    __shared__ int2 ls[SORT_CAP];
    __shared__ int lo_[SORT_CAP];
    __shared__ int cnt[BD];
    __shared__ int cur[BD];
    int b = blockIdx.x;
    int e0 = bbase[b], e1 = bbase[b + 1], n = e1 - e0;
    if (threadIdx.x < BD) cnt[threadIdx.x] = 0;
    __syncthreads();
    if (n <= SORT_CAP) {
        for (int i = threadIdx.x; i < n; i += 256) {
            int2 r = recA[e0 + i];
            ls[i] = r;
            atomicAdd(&cnt[(r.x >> 17) & 63], 1);
        }
        __syncthreads();
        if (threadIdx.x < 64) {
            int v = cnt[threadIdx.x];
            int inc = v;
#pragma unroll
            for (int s = 1; s < 64; s <<= 1) {
                int t = __shfl_up(inc, s, 64);
                if ((int)threadIdx.x >= s) inc += t;
            }
            int excl = inc - v;
            cur[threadIdx.x] = excl;
            int node = b * BD + (int)threadIdx.x;
            if (node < N) off[node] = e0 + excl;
        }
        if (threadIdx.x == 64 && b == (int)gridDim.x - 1) off[N] = E;
        __syncthreads();
        for (int i = threadIdx.x; i < n; i += 256) {
            int2 r = ls[i];
            int p = atomicAdd(&cur[(r.x >> 17) & 63], 1);
            lo_[p] = pack_rec(r.x & 0x1FFFF, __int_as_float(r.y));
        }
        __syncthreads();
        for (int i = threadIdx.x; i < n; i += 256)
            recB[e0 + i] = lo_[i];          // coalesced
    } else {
        // exact fallback (statistically unreachable): 2-pass global
        for (int i = threadIdx.x; i < n; i += 256)
            atomicAdd(&cnt[(recA[e0 + i].x >> 17) & 63], 1);
        __syncthreads();
        if (threadIdx.x < 64) {
            int v = cnt[threadIdx.x];
            int inc = v;
#pragma unroll
            for (int s = 1; s < 64; s <<= 1) {
                int t = __shfl_up(inc, s, 64);
                if ((int)threadIdx.x >= s) inc += t;
            }
            int excl = inc - v;
            cur[threadIdx.x] = excl;
            int node = b * BD + (int)threadIdx.x;
            if (node < N) off[node] = e0 + excl;
        }
        if (threadIdx.x == 64 && b == (int)gridDim.x - 1) off[N] = E;
        __syncthreads();
        for (int i = threadIdx.x; i < n; i += 256) {
            int2 r = recA[e0 + i];
            int p = atomicAdd(&cur[(r.x >> 17) & 63], 1);
            recB[e0 + p] = pack_rec(r.x & 0x1FFFF, __int_as_float(r.y));
        }
    }
}

// ---------------- pull: wave per node, 16 groups x 4 lanes x uint2 --------
// S = bf16 rows (16 x bf16 = 32B). GACT: value = leaky(S[src]+bg).
// OMODE: 0 -> write bf16 row; 1 -> fp32 log_softmax(+bo) row;
//        2 -> fused gemm23: t3 = leaky(a2@W2+b2)@W3, write bf16 row.
#define EV_DEQ (1.f / 32768.f)
template<int GACT, int OMODE>
__global__ __launch_bounds__(256) void pull_w(const int* __restrict__ off,
                                              const int* __restrict__ rec,
                                              const unsigned short* __restrict__ S,
                                              const float* __restrict__ bg,
                                              const float* __restrict__ bo,
                                              const float* __restrict__ W2,
                                              const float* __restrict__ b2f,
                                              const float* __restrict__ W3,
                                              void* __restrict__ Ovp, int N) {
    int wid = (blockIdx.x * 256 + (int)threadIdx.x) >> 6;
    int lane = threadIdx.x & 63;
    if (wid >= N) return;
    int q = lane & 3, g = lane >> 2;
    int e0 = off[wid], e1 = off[wid + 1];
    float4 bv = make_float4(0, 0, 0, 0);
    if (GACT) bv = *reinterpret_cast<const float4*>(bg + q * 4);
    const uint2* Sp = reinterpret_cast<const uint2*>(S);   // 4 uint2 per row
    float ax = 0.f, ay = 0.f, az = 0.f, aw = 0.f;
    int e = e0 + g;
    for (; e + 16 < e1; e += 32) {
        unsigned r0 = (unsigned)rec[e], r1 = (unsigned)rec[e + 16];
        uint2 u0 = Sp[(size_t)(r0 >> 15) * 4 + q];
        uint2 u1 = Sp[(size_t)(r1 >> 15) * 4 + q];
        float v0 = (float)(r0 & 32767u) * EV_DEQ;
        float v1 = (float)(r1 & 32767u) * EV_DEQ;
        float s0x = bf_lo(u0.x), s0y = bf_hi(u0.x), s0z = bf_lo(u0.y), s0w = bf_hi(u0.y);
        float s1x = bf_lo(u1.x), s1y = bf_hi(u1.x), s1z = bf_lo(u1.y), s1w = bf_hi(u1.y);
        if (GACT) {
            s0x += bv.x; s0x = s0x > 0.f ? s0x : 0.01f * s0x;
            s0y += bv.y; s0y = s0y > 0.f ? s0y : 0.01f * s0y;
            s0z += bv.z; s0z = s0z > 0.f ? s0z : 0.01f * s0z;
            s0w += bv.w; s0w = s0w > 0.f ? s0w : 0.01f * s0w;
            s1x += bv.x; s1x = s1x > 0.f ? s1x : 0.01f * s1x;
            s1y += bv.y; s1y = s1y > 0.f ? s1y : 0.01f * s1y;
            s1z += bv.z; s1z = s1z > 0.f ? s1z : 0.01f * s1z;
            s1w += bv.w; s1w = s1w > 0.f ? s1w : 0.01f * s1w;
        }
        ax += v0 * s0x; ay += v0 * s0y; az += v0 * s0z; aw += v0 * s0w;
        ax += v1 * s1x; ay += v1 * s1y; az += v1 * s1z; aw += v1 * s1w;
    }
    if (e < e1) {
        unsigned r0 = (unsigned)rec[e];
        uint2 u0 = Sp[(size_t)(r0 >> 15) * 4 + q];
        float v0 = (float)(r0 & 32767u) * EV_DEQ;
        float s0x = bf_lo(u0.x), s0y = bf_hi(u0.x), s0z = bf_lo(u0.y), s0w = bf_hi(u0.y);
        if (GACT) {
            s0x += bv.x; s0x = s0x > 0.f ? s0x : 0.01f * s0x;
            s0y += bv.y; s0y = s0y > 0.f ? s0y : 0.01f * s0y;
            s0z += bv.z; s0z = s0z > 0.f ? s0z : 0.01f * s0z;
            s0w += bv.w; s0w = s0w > 0.f ? s0w : 0.01f * s0w;
        }
        ax += v0 * s0x; ay += v0 * s0y; az += v0 * s0z; aw += v0 * s0w;
    }
    // reduce across the 16 edge groups (lane bits 2..5)
#pragma unroll
    for (int m = 4; m <= 32; m <<= 1) {
        ax += __shfl_xor(ax, m);
        ay += __shfl_xor(ay, m);
        az += __shfl_xor(az, m);
        aw += __shfl_xor(aw, m);
    }
    if (OMODE == 0) {
        if (lane < 4) {
            unsigned short* O = (unsigned short*)Ovp;
            uint2 o;
            o.x = pack2bf(ax, ay);
            o.y = pack2bf(az, aw);
            reinterpret_cast<uint2*>(O + (size_t)wid * 16)[lane] = o;
        }
    } else if (OMODE == 1) {
        float* O = (float*)Ovp;
        float4 b3v = *reinterpret_cast<const float4*>(bo + q * 4);
        float x0 = ax + b3v.x, x1 = ay + b3v.y, x2 = az + b3v.z, x3 = aw + b3v.w;
        float m = fmaxf(fmaxf(x0, x1), fmaxf(x2, x3));
        m = fmaxf(m, __shfl_xor(m, 1));
        m = fmaxf(m, __shfl_xor(m, 2));
        float ss = __expf(x0 - m) + __expf(x1 - m) + __expf(x2 - m) + __expf(x3 - m);
        ss += __shfl_xor(ss, 1);
        ss += __shfl_xor(ss, 2);
        float lse = m + __logf(ss);
        if (lane < 4)
            *reinterpret_cast<float4*>(O + (size_t)wid * 16 + lane * 4) =
                make_float4(x0 - lse, x1 - lse, x2 - lse, x3 - lse);
    } else {
        // ---- fused gemm23: wave holds full a2 row; t3 = leaky(a2@W2+b2)@W3
        float a[16];
#pragma unroll
        for (int p = 0; p < 4; ++p) {
            a[4 * p + 0] = __shfl(ax, p);
            a[4 * p + 1] = __shfl(ay, p);
            a[4 * p + 2] = __shfl(az, p);
            a[4 * p + 3] = __shfl(aw, p);
        }
        float h = b2f[lane];
#pragma unroll
        for (int k = 0; k < 16; ++k) h += a[k] * W2[k * 64 + lane];
        h = h > 0.f ? h : 0.01f * h;
        float o[16];
#pragma unroll
        for (int c = 0; c < 16; ++c) o[c] = h * W3[lane * 16 + c];
#pragma unroll
        for (int m2 = 1; m2 < 64; m2 <<= 1) {
#pragma unroll
            for (int c = 0; c < 16; ++c) o[c] += __shfl_xor(o[c], m2);
        }
        if (lane < 4) {
            unsigned short* O = (unsigned short*)Ovp;
            uint2 ov;
            ov.x = pack2bf(o[lane * 4 + 0], o[lane * 4 + 1]);
            ov.y = pack2bf(o[lane * 4 + 2], o[lane * 4 + 3]);
            reinterpret_cast<uint2*>(O + (size_t)wid * 16)[lane] = ov;
        }
    }
}

extern "C" void kernel_launch(void* const* d_in, const int* in_sizes, int n_in,
                              void* d_out, int out_size, void* d_ws, size_t ws_size,
                              hipStream_t stream) {
    const float* x   = (const float*)d_in[0];
    const int*   src = (const int*)d_in[1];
    const int*   dst = (const int*)d_in[2];
    const float* ev  = (const float*)d_in[3];
    const float* W1  = (const float*)d_in[4];
    const float* b1  = (const float*)d_in[5];
    const float* W2  = (const float*)d_in[6];
    const float* b2  = (const float*)d_in[7];
    const float* W3  = (const float*)d_in[8];
    const float* b3  = (const float*)d_in[9];
    float* out = (float*)d_out;

    const int N = in_sizes[0] / 512;   // 100000
    const int E = in_sizes[1];         // 3200000

    // workspace layout (recA recycled as B1 after sort2); bf16 tables
    unsigned short* B0 = (unsigned short*)d_ws;        // N x 16 bf16 (t1 / t3)
    int2*  recA  = (int2*)(B0 + (size_t)N * 16);       // E {src|dl<<17, ev}
    int*   recB  = (int*)(recA + E);                   // E node-sorted src<<15|ev15
    int*   C     = recB + E;                           // NBLK x NBKT
    int*   btot  = C + (size_t)NBLK * NBKT;            // NBKT
    int*   bbase = btot + NBKT;                        // NBKT+1
    int*   off   = bbase + (NBKT + 1);                 // N+1
    int*   done  = off + (N + 1);                      // 1 (p2a tail counter)
    unsigned short* B1 = (unsigned short*)recA;        // N x 16 bf16 (a1)

    auto blks = [](long n) { return (int)((n + 255) / 256); };
    const int ntiles = (N + 15) / 16;               // 6250 MFMA row-tiles
    const int NB_gemm = (ntiles + 3) / 4;           // 4 waves/block -> 1563
    const int pull_blocks = blks((long)N * 64);     // wave per node

    // ---- partition build (no global fp32 atomics) + MFMA gemm1 ----
    p1g_k<<<NB_gemm + NBLK, 256, 0, stream>>>(x, W1, B0, dst, C, done, N, E, NB_gemm);
    p2a<<<(NBKT + 15) / 16, 256, 0, stream>>>(C, btot, bbase, done);
    p3_place<<<NBLK, 256, 0, stream>>>(src, dst, ev, C, bbase, recA, E);
    sort2_k<<<NBKT, 256, 0, stream>>>(bbase, recA, recB, off, N, E);

    // ---- layer 1 aggregate: a1 = spmm(t1) (bf16 out) ----
    pull_w<0, 0><<<pull_blocks, 256, 0, stream>>>(off, recB, B0, nullptr, nullptr,
                                                  nullptr, nullptr, nullptr, B1, N);

    // ---- layer 2 aggregate + fused gemm23: t3 = leaky(spmm(leaky(a1+b1))@W2+b2)@W3 ----
    pull_w<1, 2><<<pull_blocks, 256, 0, stream>>>(off, recB, B1, b1, nullptr,
                                                  W2, b2, W3, B0, N);

    // ---- layer 3 aggregate + bias + log_softmax -> out (fp32) ----
    pull_w<0, 1><<<pull_blocks, 256, 0, stream>>>(off, recB, B0, nullptr, b3,
                                                  nullptr, nullptr, nullptr, out, N);
}

// Round 19
// 263.830 us; speedup vs baseline: 1.3102x; 1.3102x over previous
//
#include <hip/hip_runtime.h>
#include <cmath>

// GCN: 3 x (dense GEMM <-> pull-SpMM) + fused log_softmax.
// Build: atomic-free two-level counting partition (bucket = dst>>6) ->
// within-bucket counting sort (sort2) -> compact per-node CSR with 4-byte
// records (src 17b | ev 15b fixed-point). gemm1 = MFMA 16x16x32 bf16.
// All pull tables bf16 (3.2MB -> L2-resident). XCD-aware chunk swizzle in
// p3 (write-side line merge in per-XCD L2).
// Round-19: REVERT to round-14 exact (264us best). The gemm23-in-pull2
// epilogue fusion (r18) was VALU-bound (96 shuffle+adds/wave, 148us); the
// cooperative mega-kernel (r16) serialized pulls (828us). Separate
// thread-per-row gemm23_k (~6us) is the right structure.
// Pulls: wave-per-node, 16 groups x 4 lanes x uint2(4xbf16). No global
// atomics. Algebra: spmm(A, h@W) == spmm(A, h)@W -> aggregate in dim 16.
// Layer-1 activation recomputed inside layer-2's gather.

#define BD 64                            // dsts per bucket
#define NBKT 1563                        // ceil(100000/64)
#define NBLK 1024                        // partition blocks (8 XCDs x 128)
#define SORT_CAP 3072                    // max bucket edges staged in LDS

typedef __attribute__((ext_vector_type(8))) short bf16x8;
typedef __attribute__((ext_vector_type(4))) float f32x4;

__device__ __forceinline__ short to_bf16(float f) {
    unsigned u = __float_as_uint(f);
    u += 0x8000u;                         // round-half-up
    return (short)(u >> 16);
}
__device__ __forceinline__ unsigned pack2bf(float a, float b) {
    return (unsigned)(unsigned short)to_bf16(a) |
           ((unsigned)(unsigned short)to_bf16(b) << 16);
}
__device__ __forceinline__ float bf_lo(unsigned v) { return __uint_as_float(v << 16); }
__device__ __forceinline__ float bf_hi(unsigned v) { return __uint_as_float(v & 0xFFFF0000u); }

// ---------------- fused: gemm1 MFMA (x@W1 -> t1 bf16) + bucket hist -------
__global__ __launch_bounds__(256) void p1g_k(const float* __restrict__ x,
                                             const float* __restrict__ W1,
                                             unsigned short* __restrict__ t1,
                                             const int* __restrict__ dst,
                                             int* __restrict__ C,
                                             int N, int E, int NB_gemm) {
    __shared__ __align__(16) unsigned short wlds[8192];  // 16 KB (union w/ hist)
    if ((int)blockIdx.x < NB_gemm) {
        // --- stage W1 as bf16 B-fragments: [kt][kg][col][j] (j contiguous) ---
        {
            int t = threadIdx.x;
            int kt = t >> 4, col = t & 15;
#pragma unroll
            for (int j = 0; j < 32; ++j) {
                int k = kt * 32 + j;
                float v = W1[(size_t)k * 16 + col];
                wlds[(((kt * 4 + (j >> 3)) * 16 + col) << 3) + (j & 7)] =
                    (unsigned short)to_bf16(v);
            }
        }
        __syncthreads();
        int wid = (blockIdx.x * 256 + (int)threadIdx.x) >> 6;  // global wave id
        int ntiles = (N + 15) >> 4;
        if (wid >= ntiles) return;
        int lane = threadIdx.x & 63;
        int m = lane & 15, kg = lane >> 4;
        int r = wid * 16 + m;
        int rc = r < N ? r : N - 1;                      // clamp (no OOB addr)
        const float4* Xv = reinterpret_cast<const float4*>(x + (size_t)rc * 512);
        f32x4 acc = {0.f, 0.f, 0.f, 0.f};
#pragma unroll
        for (int kt = 0; kt < 16; ++kt) {
            float4 xa = Xv[kt * 8 + kg * 2];
            float4 xb = Xv[kt * 8 + kg * 2 + 1];
            bf16x8 a;
            a[0] = to_bf16(xa.x); a[1] = to_bf16(xa.y);
            a[2] = to_bf16(xa.z); a[3] = to_bf16(xa.w);
            a[4] = to_bf16(xb.x); a[5] = to_bf16(xb.y);
            a[6] = to_bf16(xb.z); a[7] = to_bf16(xb.w);
            bf16x8 b = *reinterpret_cast<const bf16x8*>(
                &wlds[((kt * 4 + kg) * 16 + m) << 3]);
            acc = __builtin_amdgcn_mfma_f32_16x16x32_bf16(a, b, acc, 0, 0, 0);
        }
        // D: col = lane&15 (=m), row = kg*4 + i
#pragma unroll
        for (int i = 0; i < 4; ++i) {
            int ro = wid * 16 + kg * 4 + i;
            if (ro < N) t1[(size_t)ro * 16 + m] = (unsigned short)to_bf16(acc[i]);
        }
        return;
    }
    int* h = (int*)wlds;
    int k = (int)blockIdx.x - NB_gemm;
    for (int i = threadIdx.x; i < NBKT; i += 256) h[i] = 0;
    __syncthreads();
    int epb = (E + NBLK - 1) / NBLK;
    int lo = k * epb, hi = min(lo + epb, E);
    for (int e = lo + (int)threadIdx.x; e < hi; e += 256)
        atomicAdd(&h[dst[e] >> 6], 1);
    __syncthreads();
    for (int i = threadIdx.x; i < NBKT; i += 256)
        C[(size_t)k * NBKT + i] = h[i];
}

// ---------------- P2a: coalesced scan over origin blocks per bucket -------
__global__ __launch_bounds__(256) void p2a(int* __restrict__ C,
                                           int* __restrict__ btot) {
    __shared__ int s[16][17];
    int bs = threadIdx.x & 15, ki = threadIdx.x >> 4;
    int b = blockIdx.x * 16 + bs;
    bool ok = b < NBKT;
    int sum = 0;
    if (ok) {
        for (int j = 0; j < 64; ++j)
            sum += C[(size_t)(ki * 64 + j) * NBKT + b];
    }
    s[ki][bs] = sum;
    __syncthreads();
    int base = 0;
    for (int j = 0; j < ki; ++j) base += s[j][bs];
    if (ok) {
        if (ki == 15) btot[b] = base + sum;
        int run = base;
        for (int j = 0; j < 64; ++j) {
            size_t idx = (size_t)(ki * 64 + j) * NBKT + b;
            int v = C[idx];
            C[idx] = run;                 // exclusive offset
            run += v;
        }
    }
}

// ---------------- P2b: exclusive scan of bucket totals -> bucket bases ----
__global__ __launch_bounds__(256) void p2b(const int* __restrict__ btot,
                                           int* __restrict__ bbase, int E) {
    __shared__ int ps[256];
    int loc[8], sum = 0;
    int base = (int)threadIdx.x * 8;     // 2048 >= NBKT+1
#pragma unroll
    for (int j = 0; j < 8; ++j) {
        int i = base + j;
        int v = (i < NBKT) ? btot[i] : 0;
        loc[j] = sum; sum += v;
    }
    ps[threadIdx.x] = sum;
    __syncthreads();
    for (int st = 1; st < 256; st <<= 1) {
        int tv = (threadIdx.x >= (unsigned)st) ? ps[threadIdx.x - st] : 0;
        __syncthreads();
        ps[threadIdx.x] += tv;
        __syncthreads();
    }
    int prev = ps[threadIdx.x] - sum;
#pragma unroll
    for (int j = 0; j < 8; ++j) {
        int i = base + j;
        if (i <= NBKT) bbase[i] = prev + loc[j];
    }
}

// ---------------- P3: scatter bucket-sorted records (LDS cursors) ---------
// XCD swizzle: chunks 128k..128k+127 all run on XCD k, so their adjacent
// record slots merge into full lines in that XCD's L2.
__global__ __launch_bounds__(256) void p3_place(const int* __restrict__ src,
                                                const int* __restrict__ dst,
                                                const float* __restrict__ ev,
                                                const int* __restrict__ C,
                                                const int* __restrict__ bbase,
                                                int2* __restrict__ recA, int E) {
    __shared__ int cur[NBKT];
    int bid = (int)blockIdx.x;
    int k = ((bid & 7) << 7) | (bid >> 3);   // (bid%8)*128 + bid/8
    for (int i = threadIdx.x; i < NBKT; i += 256)
        cur[i] = bbase[i] + C[(size_t)k * NBKT + i];
    __syncthreads();
    int epb = (E + NBLK - 1) / NBLK;
    int lo = k * epb, hi = min(lo + epb, E);
    for (int e = lo + (int)threadIdx.x; e < hi; e += 256) {
        int d = dst[e];
        int p = atomicAdd(&cur[d >> 6], 1);   // LDS ds_add_rtn
        recA[p] = make_int2(src[e] | ((d & 63) << 17), __float_as_int(ev[e]));
    }
}

// ---------------- sort2: within-bucket counting sort -> 4B-record CSR -----
__device__ __forceinline__ int pack_rec(int srcbits, float evf) {
    int q = (int)(evf * 32768.f + 0.5f);
    q = q > 32767 ? 32767 : q;
    return (srcbits << 15) | q;
}

__global__ __launch_bounds__(256) void sort2_k(const int* __restrict__ bbase,
                                               const int2* __restrict__ recA,
                                               int* __restrict__ recB,
                                               int* __restrict__ off,
                                               int N, int E) {
    __shared__ int2 ls[SORT_CAP];
    __shared__ int lo_[SORT_CAP];
    __shared__ int cnt[BD];
    __shared__ int cur[BD];
    int b = blockIdx.x;
    int e0 = bbase[b], e1 = bbase[b + 1], n = e1 - e0;
    if (threadIdx.x < BD) cnt[threadIdx.x] = 0;
    __syncthreads();
    if (n <= SORT_CAP) {
        for (int i = threadIdx.x; i < n; i += 256) {
            int2 r = recA[e0 + i];
            ls[i] = r;
            atomicAdd(&cnt[(r.x >> 17) & 63], 1);
        }
        __syncthreads();
        if (threadIdx.x < 64) {
            int v = cnt[threadIdx.x];
            int inc = v;
#pragma unroll
            for (int s = 1; s < 64; s <<= 1) {
                int t = __shfl_up(inc, s, 64);
                if ((int)threadIdx.x >= s) inc += t;
            }
            int excl = inc - v;
            cur[threadIdx.x] = excl;
            int node = b * BD + (int)threadIdx.x;
            if (node < N) off[node] = e0 + excl;
        }
        if (threadIdx.x == 64 && b == (int)gridDim.x - 1) off[N] = E;
        __syncthreads();
        for (int i = threadIdx.x; i < n; i += 256) {
            int2 r = ls[i];
            int p = atomicAdd(&cur[(r.x >> 17) & 63], 1);
            lo_[p] = pack_rec(r.x & 0x1FFFF, __int_as_float(r.y));
        }
        __syncthreads();
        for (int i = threadIdx.x; i < n; i += 256)
            recB[e0 + i] = lo_[i];          // coalesced
    } else {
        // exact fallback (statistically unreachable): 2-pass global
        for (int i = threadIdx.x; i < n; i += 256)
            atomicAdd(&cnt[(recA[e0 + i].x >> 17) & 63], 1);
        __syncthreads();
        if (threadIdx.x < 64) {
            int v = cnt[threadIdx.x];
            int inc = v;
#pragma unroll
            for (int s = 1; s < 64; s <<= 1) {
                int t = __shfl_up(inc, s, 64);
                if ((int)threadIdx.x >= s) inc += t;
            }
            int excl = inc - v;
            cur[threadIdx.x] = excl;
            int node = b * BD + (int)threadIdx.x;
            if (node < N) off[node] = e0 + excl;
        }
        if (threadIdx.x == 64 && b == (int)gridDim.x - 1) off[N] = E;
        __syncthreads();
        for (int i = threadIdx.x; i < n; i += 256) {
            int2 r = recA[e0 + i];
            int p = atomicAdd(&cur[(r.x >> 17) & 63], 1);
            recB[e0 + p] = pack_rec(r.x & 0x1FFFF, __int_as_float(r.y));
        }
    }
}

// ---------------- pull: wave per node, 16 groups x 4 lanes x uint2 --------
// S = bf16 rows (16 x bf16 = 32B). GACT: value = leaky(S[src]+bg).
// OMODE: 0 -> write bf16 row; 1 -> write fp32 log_softmax(+bo) row.
#define EV_DEQ (1.f / 32768.f)
template<int GACT, int OMODE>
__global__ __launch_bounds__(256) void pull_w(const int* __restrict__ off,
                                              const int* __restrict__ rec,
                                              const unsigned short* __restrict__ S,
                                              const float* __restrict__ bg,
                                              const float* __restrict__ bo,
                                              void* __restrict__ Ovp, int N) {
    int wid = (blockIdx.x * 256 + (int)threadIdx.x) >> 6;
    int lane = threadIdx.x & 63;
    if (wid >= N) return;
    int q = lane & 3, g = lane >> 2;
    int e0 = off[wid], e1 = off[wid + 1];
    float4 bv = make_float4(0, 0, 0, 0);
    if (GACT) bv = *reinterpret_cast<const float4*>(bg + q * 4);
    const uint2* Sp = reinterpret_cast<const uint2*>(S);   // 4 uint2 per row
    float ax = 0.f, ay = 0.f, az = 0.f, aw = 0.f;
    int e = e0 + g;
    for (; e + 16 < e1; e += 32) {
        unsigned r0 = (unsigned)rec[e], r1 = (unsigned)rec[e + 16];
        uint2 u0 = Sp[(size_t)(r0 >> 15) * 4 + q];
        uint2 u1 = Sp[(size_t)(r1 >> 15) * 4 + q];
        float v0 = (float)(r0 & 32767u) * EV_DEQ;
        float v1 = (float)(r1 & 32767u) * EV_DEQ;
        float s0x = bf_lo(u0.x), s0y = bf_hi(u0.x), s0z = bf_lo(u0.y), s0w = bf_hi(u0.y);
        float s1x = bf_lo(u1.x), s1y = bf_hi(u1.x), s1z = bf_lo(u1.y), s1w = bf_hi(u1.y);
        if (GACT) {
            s0x += bv.x; s0x = s0x > 0.f ? s0x : 0.01f * s0x;
            s0y += bv.y; s0y = s0y > 0.f ? s0y : 0.01f * s0y;
            s0z += bv.z; s0z = s0z > 0.f ? s0z : 0.01f * s0z;
            s0w += bv.w; s0w = s0w > 0.f ? s0w : 0.01f * s0w;
            s1x += bv.x; s1x = s1x > 0.f ? s1x : 0.01f * s1x;
            s1y += bv.y; s1y = s1y > 0.f ? s1y : 0.01f * s1y;
            s1z += bv.z; s1z = s1z > 0.f ? s1z : 0.01f * s1z;
            s1w += bv.w; s1w = s1w > 0.f ? s1w : 0.01f * s1w;
        }
        ax += v0 * s0x; ay += v0 * s0y; az += v0 * s0z; aw += v0 * s0w;
        ax += v1 * s1x; ay += v1 * s1y; az += v1 * s1z; aw += v1 * s1w;
    }
    if (e < e1) {
        unsigned r0 = (unsigned)rec[e];
        uint2 u0 = Sp[(size_t)(r0 >> 15) * 4 + q];
        float v0 = (float)(r0 & 32767u) * EV_DEQ;
        float s0x = bf_lo(u0.x), s0y = bf_hi(u0.x), s0z = bf_lo(u0.y), s0w = bf_hi(u0.y);
        if (GACT) {
            s0x += bv.x; s0x = s0x > 0.f ? s0x : 0.01f * s0x;
            s0y += bv.y; s0y = s0y > 0.f ? s0y : 0.01f * s0y;
            s0z += bv.z; s0z = s0z > 0.f ? s0z : 0.01f * s0z;
            s0w += bv.w; s0w = s0w > 0.f ? s0w : 0.01f * s0w;
        }
        ax += v0 * s0x; ay += v0 * s0y; az += v0 * s0z; aw += v0 * s0w;
    }
    // reduce across the 16 edge groups (lane bits 2..5)
#pragma unroll
    for (int m = 4; m <= 32; m <<= 1) {
        ax += __shfl_xor(ax, m);
        ay += __shfl_xor(ay, m);
        az += __shfl_xor(az, m);
        aw += __shfl_xor(aw, m);
    }
    if (OMODE == 0) {
        if (lane < 4) {
            unsigned short* O = (unsigned short*)Ovp;
            uint2 o;
            o.x = pack2bf(ax, ay);
            o.y = pack2bf(az, aw);
            reinterpret_cast<uint2*>(O + (size_t)wid * 16)[lane] = o;
        }
    } else {
        float* O = (float*)Ovp;
        float4 b3v = *reinterpret_cast<const float4*>(bo + q * 4);
        float x0 = ax + b3v.x, x1 = ay + b3v.y, x2 = az + b3v.z, x3 = aw + b3v.w;
        float m = fmaxf(fmaxf(x0, x1), fmaxf(x2, x3));
        m = fmaxf(m, __shfl_xor(m, 1));
        m = fmaxf(m, __shfl_xor(m, 2));
        float ss = __expf(x0 - m) + __expf(x1 - m) + __expf(x2 - m) + __expf(x3 - m);
        ss += __shfl_xor(ss, 1);
        ss += __shfl_xor(ss, 2);
        float lse = m + __logf(ss);
        if (lane < 4)
            *reinterpret_cast<float4*>(O + (size_t)wid * 16 + lane * 4) =
                make_float4(x0 - lse, x1 - lse, x2 - lse, x3 - lse);
    }
}

// ---------------- fused gemm2+leaky+gemm3 (bf16 in/out) -------------------
__global__ __launch_bounds__(256) void gemm23_k(const unsigned short* __restrict__ A,
                                                const float* __restrict__ W2,
                                                const float* __restrict__ b2,
                                                const float* __restrict__ W3,
                                                unsigned short* __restrict__ T3, int N) {
    int row = blockIdx.x * 256 + threadIdx.x;
    if (row >= N) return;
    float a[16];
    const uint2* Av = reinterpret_cast<const uint2*>(A + (size_t)row * 16);
#pragma unroll
    for (int qq = 0; qq < 4; ++qq) {
        uint2 v = Av[qq];
        a[4*qq+0] = bf_lo(v.x); a[4*qq+1] = bf_hi(v.x);
        a[4*qq+2] = bf_lo(v.y); a[4*qq+3] = bf_hi(v.y);
    }
    float h[64];
#pragma unroll
    for (int j = 0; j < 64; ++j) h[j] = b2[j];
#pragma unroll
    for (int k = 0; k < 16; ++k)
#pragma unroll
        for (int j = 0; j < 64; ++j)
            h[j] += a[k] * W2[(size_t)k * 64 + j];
#pragma unroll
    for (int j = 0; j < 64; ++j) h[j] = h[j] > 0.f ? h[j] : 0.01f * h[j];
    float o[16];
#pragma unroll
    for (int c = 0; c < 16; ++c) o[c] = 0.f;
#pragma unroll
    for (int j = 0; j < 64; ++j)
#pragma unroll
        for (int c = 0; c < 16; ++c)
            o[c] += h[j] * W3[(size_t)j * 16 + c];
    unsigned r[8];
#pragma unroll
    for (int i = 0; i < 8; ++i) r[i] = pack2bf(o[2*i], o[2*i+1]);
    uint4* Tv = reinterpret_cast<uint4*>(T3 + (size_t)row * 16);
    Tv[0] = make_uint4(r[0], r[1], r[2], r[3]);
    Tv[1] = make_uint4(r[4], r[5], r[6], r[7]);
}

extern "C" void kernel_launch(void* const* d_in, const int* in_sizes, int n_in,
                              void* d_out, int out_size, void* d_ws, size_t ws_size,
                              hipStream_t stream) {
    const float* x   = (const float*)d_in[0];
    const int*   src = (const int*)d_in[1];
    const int*   dst = (const int*)d_in[2];
    const float* ev  = (const float*)d_in[3];
    const float* W1  = (const float*)d_in[4];
    const float* b1  = (const float*)d_in[5];
    const float* W2  = (const float*)d_in[6];
    const float* b2  = (const float*)d_in[7];
    const float* W3  = (const float*)d_in[8];
    const float* b3  = (const float*)d_in[9];
    float* out = (float*)d_out;

    const int N = in_sizes[0] / 512;   // 100000
    const int E = in_sizes[1];         // 3200000

    // workspace layout (recA recycled as B1/B2 after sort2); bf16 tables
    unsigned short* B0 = (unsigned short*)d_ws;        // N x 16 bf16 (t1 / t3)
    int2*  recA  = (int2*)(B0 + (size_t)N * 16);       // E {src|dl<<17, ev}
    int*   recB  = (int*)(recA + E);                   // E node-sorted src<<15|ev15
    int*   C     = recB + E;                           // NBLK x NBKT
    int*   btot  = C + (size_t)NBLK * NBKT;            // NBKT
    int*   bbase = btot + NBKT;                        // NBKT+1
    int*   off   = bbase + (NBKT + 1);                 // N+1
    unsigned short* B1 = (unsigned short*)recA;        // N x 16 bf16 (a1)
    unsigned short* B2 = B1 + (size_t)N * 16;          // N x 16 bf16 (a2)

    auto blks = [](long n) { return (int)((n + 255) / 256); };
    const int ntiles = (N + 15) / 16;               // 6250 MFMA row-tiles
    const int NB_gemm = (ntiles + 3) / 4;           // 4 waves/block -> 1563
    const int pull_blocks = blks((long)N * 64);     // wave per node

    // ---- partition build (no global atomics) + MFMA gemm1 ----
    p1g_k<<<NB_gemm + NBLK, 256, 0, stream>>>(x, W1, B0, dst, C, N, E, NB_gemm);
    p2a<<<(NBKT + 15) / 16, 256, 0, stream>>>(C, btot);
    p2b<<<1, 256, 0, stream>>>(btot, bbase, E);
    p3_place<<<NBLK, 256, 0, stream>>>(src, dst, ev, C, bbase, recA, E);
    sort2_k<<<NBKT, 256, 0, stream>>>(bbase, recA, recB, off, N, E);

    // ---- layer 1 aggregate: a1 = spmm(t1) (bf16 out) ----
    pull_w<0, 0><<<pull_blocks, 256, 0, stream>>>(off, recB, B0, nullptr, nullptr, B1, N);

    // ---- layer 2 aggregate: a2 = spmm(leaky(a1+b1)) (bf16 out) ----
    pull_w<1, 0><<<pull_blocks, 256, 0, stream>>>(off, recB, B1, b1, nullptr, B2, N);

    // ---- t3 = leaky(a2@W2+b2)@W3 (bf16 in/out) ----
    gemm23_k<<<NB_gemm, 256, 0, stream>>>(B2, W2, b2, W3, B0, N);

    // ---- layer 3 aggregate + bias + log_softmax -> out (fp32) ----
    pull_w<0, 1><<<pull_blocks, 256, 0, stream>>>(off, recB, B0, nullptr, b3, out, N);
}

// Round 20
// 263.667 us; speedup vs baseline: 1.3110x; 1.0006x over previous
//
#include <hip/hip_runtime.h>
#include <cmath>

// GCN: 3 x (dense GEMM <-> pull-SpMM) + fused log_softmax.
// Build: atomic-free two-level counting partition (bucket = dst>>7) ->
// within-bucket counting sort (sort2) -> compact per-node CSR with 4-byte
// records (src 17b | ev 15b fixed-point). gemm1 = MFMA 16x16x32 bf16.
// All pull tables bf16 (3.2MB -> L2-resident). XCD-aware chunk swizzle in
// p3 (write-side line merge in per-XCD L2).
// Round-20 change: BD 64 -> 128 (NBKT 1563 -> 782). p3's scattered-record
// write amplification (~4x: 100MB WRITE for 25.6MB payload) comes from
// each 64B line being assembled by 4 different chunks (2 records each).
// Doubling bucket size doubles records/(chunk,bucket) to ~4 = 32B pieces,
// halving writers per line. Also halves the C matrix and p3's LDS cursors.
// sort2 handles 128-dst buckets (SORT_CAP 6144, ~75KB LDS, 2 blocks/CU).
// Pulls: wave-per-node, 16 groups x 4 lanes x uint2(4xbf16). No global
// atomics. Algebra: spmm(A, h@W) == spmm(A, h)@W -> aggregate in dim 16.
// Layer-1 activation recomputed inside layer-2's gather.

#define BD 128                           // dsts per bucket
#define NBKT 782                         // ceil(100000/128)
#define NBLK 1024                        // partition blocks (8 XCDs x 128)
#define SORT_CAP 6144                    // max bucket edges staged in LDS

typedef __attribute__((ext_vector_type(8))) short bf16x8;
typedef __attribute__((ext_vector_type(4))) float f32x4;

__device__ __forceinline__ short to_bf16(float f) {
    unsigned u = __float_as_uint(f);
    u += 0x8000u;                         // round-half-up
    return (short)(u >> 16);
}
__device__ __forceinline__ unsigned pack2bf(float a, float b) {
    return (unsigned)(unsigned short)to_bf16(a) |
           ((unsigned)(unsigned short)to_bf16(b) << 16);
}
__device__ __forceinline__ float bf_lo(unsigned v) { return __uint_as_float(v << 16); }
__device__ __forceinline__ float bf_hi(unsigned v) { return __uint_as_float(v & 0xFFFF0000u); }

// ---------------- fused: gemm1 MFMA (x@W1 -> t1 bf16) + bucket hist -------
__global__ __launch_bounds__(256) void p1g_k(const float* __restrict__ x,
                                             const float* __restrict__ W1,
                                             unsigned short* __restrict__ t1,
                                             const int* __restrict__ dst,
                                             int* __restrict__ C,
                                             int N, int E, int NB_gemm) {
    __shared__ __align__(16) unsigned short wlds[8192];  // 16 KB (union w/ hist)
    if ((int)blockIdx.x < NB_gemm) {
        // --- stage W1 as bf16 B-fragments: [kt][kg][col][j] (j contiguous) ---
        {
            int t = threadIdx.x;
            int kt = t >> 4, col = t & 15;
#pragma unroll
            for (int j = 0; j < 32; ++j) {
                int k = kt * 32 + j;
                float v = W1[(size_t)k * 16 + col];
                wlds[(((kt * 4 + (j >> 3)) * 16 + col) << 3) + (j & 7)] =
                    (unsigned short)to_bf16(v);
            }
        }
        __syncthreads();
        int wid = (blockIdx.x * 256 + (int)threadIdx.x) >> 6;  // global wave id
        int ntiles = (N + 15) >> 4;
        if (wid >= ntiles) return;
        int lane = threadIdx.x & 63;
        int m = lane & 15, kg = lane >> 4;
        int r = wid * 16 + m;
        int rc = r < N ? r : N - 1;                      // clamp (no OOB addr)
        const float4* Xv = reinterpret_cast<const float4*>(x + (size_t)rc * 512);
        f32x4 acc = {0.f, 0.f, 0.f, 0.f};
#pragma unroll
        for (int kt = 0; kt < 16; ++kt) {
            float4 xa = Xv[kt * 8 + kg * 2];
            float4 xb = Xv[kt * 8 + kg * 2 + 1];
            bf16x8 a;
            a[0] = to_bf16(xa.x); a[1] = to_bf16(xa.y);
            a[2] = to_bf16(xa.z); a[3] = to_bf16(xa.w);
            a[4] = to_bf16(xb.x); a[5] = to_bf16(xb.y);
            a[6] = to_bf16(xb.z); a[7] = to_bf16(xb.w);
            bf16x8 b = *reinterpret_cast<const bf16x8*>(
                &wlds[((kt * 4 + kg) * 16 + m) << 3]);
            acc = __builtin_amdgcn_mfma_f32_16x16x32_bf16(a, b, acc, 0, 0, 0);
        }
        // D: col = lane&15 (=m), row = kg*4 + i
#pragma unroll
        for (int i = 0; i < 4; ++i) {
            int ro = wid * 16 + kg * 4 + i;
            if (ro < N) t1[(size_t)ro * 16 + m] = (unsigned short)to_bf16(acc[i]);
        }
        return;
    }
    int* h = (int*)wlds;
    int k = (int)blockIdx.x - NB_gemm;
    for (int i = threadIdx.x; i < NBKT; i += 256) h[i] = 0;
    __syncthreads();
    int epb = (E + NBLK - 1) / NBLK;
    int lo = k * epb, hi = min(lo + epb, E);
    for (int e = lo + (int)threadIdx.x; e < hi; e += 256)
        atomicAdd(&h[dst[e] >> 7], 1);
    __syncthreads();
    for (int i = threadIdx.x; i < NBKT; i += 256)
        C[(size_t)k * NBKT + i] = h[i];
}

// ---------------- P2a: coalesced scan over origin blocks per bucket -------
__global__ __launch_bounds__(256) void p2a(int* __restrict__ C,
                                           int* __restrict__ btot) {
    __shared__ int s[16][17];
    int bs = threadIdx.x & 15, ki = threadIdx.x >> 4;
    int b = blockIdx.x * 16 + bs;
    bool ok = b < NBKT;
    int sum = 0;
    if (ok) {
        for (int j = 0; j < 64; ++j)
            sum += C[(size_t)(ki * 64 + j) * NBKT + b];
    }
    s[ki][bs] = sum;
    __syncthreads();
    int base = 0;
    for (int j = 0; j < ki; ++j) base += s[j][bs];
    if (ok) {
        if (ki == 15) btot[b] = base + sum;
        int run = base;
        for (int j = 0; j < 64; ++j) {
            size_t idx = (size_t)(ki * 64 + j) * NBKT + b;
            int v = C[idx];
            C[idx] = run;                 // exclusive offset
            run += v;
        }
    }
}

// ---------------- P2b: exclusive scan of bucket totals -> bucket bases ----
__global__ __launch_bounds__(256) void p2b(const int* __restrict__ btot,
                                           int* __restrict__ bbase, int E) {
    __shared__ int ps[256];
    int loc[8], sum = 0;
    int base = (int)threadIdx.x * 8;     // 2048 >= NBKT+1
#pragma unroll
    for (int j = 0; j < 8; ++j) {
        int i = base + j;
        int v = (i < NBKT) ? btot[i] : 0;
        loc[j] = sum; sum += v;
    }
    ps[threadIdx.x] = sum;
    __syncthreads();
    for (int st = 1; st < 256; st <<= 1) {
        int tv = (threadIdx.x >= (unsigned)st) ? ps[threadIdx.x - st] : 0;
        __syncthreads();
        ps[threadIdx.x] += tv;
        __syncthreads();
    }
    int prev = ps[threadIdx.x] - sum;
#pragma unroll
    for (int j = 0; j < 8; ++j) {
        int i = base + j;
        if (i <= NBKT) bbase[i] = prev + loc[j];
    }
}

// ---------------- P3: scatter bucket-sorted records (LDS cursors) ---------
// XCD swizzle: chunks 128k..128k+127 all run on XCD k, so their adjacent
// record slots merge into full lines in that XCD's L2.
__global__ __launch_bounds__(256) void p3_place(const int* __restrict__ src,
                                                const int* __restrict__ dst,
                                                const float* __restrict__ ev,
                                                const int* __restrict__ C,
                                                const int* __restrict__ bbase,
                                                int2* __restrict__ recA, int E) {
    __shared__ int cur[NBKT];
    int bid = (int)blockIdx.x;
    int k = ((bid & 7) << 7) | (bid >> 3);   // (bid%8)*128 + bid/8
    for (int i = threadIdx.x; i < NBKT; i += 256)
        cur[i] = bbase[i] + C[(size_t)k * NBKT + i];
    __syncthreads();
    int epb = (E + NBLK - 1) / NBLK;
    int lo = k * epb, hi = min(lo + epb, E);
    for (int e = lo + (int)threadIdx.x; e < hi; e += 256) {
        int d = dst[e];
        int p = atomicAdd(&cur[d >> 7], 1);   // LDS ds_add_rtn
        recA[p] = make_int2(src[e] | ((d & 127) << 17), __float_as_int(ev[e]));
    }
}

// ---------------- sort2: within-bucket counting sort -> 4B-record CSR -----
__device__ __forceinline__ int pack_rec(int srcbits, float evf) {
    int q = (int)(evf * 32768.f + 0.5f);
    q = q > 32767 ? 32767 : q;
    return (srcbits << 15) | q;
}

__global__ __launch_bounds__(256) void sort2_k(const int* __restrict__ bbase,
                                               const int2* __restrict__ recA,
                                               int* __restrict__ recB,
                                               int* __restrict__ off,
                                               int N, int E) {
    __shared__ int2 ls[SORT_CAP];
    __shared__ int lo_[SORT_CAP];
    __shared__ int cnt[BD];
    __shared__ int cur[BD];
    __shared__ int sc[BD];
    int b = blockIdx.x;
    int e0 = bbase[b], e1 = bbase[b + 1], n = e1 - e0;
    int t = threadIdx.x;
    if (t < BD) cnt[t] = 0;
    __syncthreads();
    if (n <= SORT_CAP) {
        for (int i = t; i < n; i += 256) {
            int2 r = recA[e0 + i];
            ls[i] = r;
            atomicAdd(&cnt[(r.x >> 17) & 127], 1);
        }
        __syncthreads();
        // 128-wide Hillis-Steele inclusive scan in LDS
        if (t < BD) sc[t] = cnt[t];
        __syncthreads();
        for (int st = 1; st < BD; st <<= 1) {
            int v = (t < BD && t >= st) ? sc[t - st] : 0;
            __syncthreads();
            if (t < BD) sc[t] += v;
            __syncthreads();
        }
        if (t < BD) {
            int excl = sc[t] - cnt[t];
            cur[t] = excl;
            int node = b * BD + t;
            if (node < N) off[node] = e0 + excl;
        }
        if (t == BD && b == (int)gridDim.x - 1) off[N] = E;
        __syncthreads();
        for (int i = t; i < n; i += 256) {
            int2 r = ls[i];
            int p = atomicAdd(&cur[(r.x >> 17) & 127], 1);
            lo_[p] = pack_rec(r.x & 0x1FFFF, __int_as_float(r.y));
        }
        __syncthreads();
        for (int i = t; i < n; i += 256)
            recB[e0 + i] = lo_[i];          // coalesced
    } else {
        // exact fallback (statistically unreachable): 2-pass global
        for (int i = t; i < n; i += 256)
            atomicAdd(&cnt[(recA[e0 + i].x >> 17) & 127], 1);
        __syncthreads();
        if (t < BD) sc[t] = cnt[t];
        __syncthreads();
        for (int st = 1; st < BD; st <<= 1) {
            int v = (t < BD && t >= st) ? sc[t - st] : 0;
            __syncthreads();
            if (t < BD) sc[t] += v;
            __syncthreads();
        }
        if (t < BD) {
            int excl = sc[t] - cnt[t];
            cur[t] = excl;
            int node = b * BD + t;
            if (node < N) off[node] = e0 + excl;
        }
        if (t == BD && b == (int)gridDim.x - 1) off[N] = E;
        __syncthreads();
        for (int i = t; i < n; i += 256) {
            int2 r = recA[e0 + i];
            int p = atomicAdd(&cur[(r.x >> 17) & 127], 1);
            recB[e0 + p] = pack_rec(r.x & 0x1FFFF, __int_as_float(r.y));
        }
    }
}

// ---------------- pull: wave per node, 16 groups x 4 lanes x uint2 --------
// S = bf16 rows (16 x bf16 = 32B). GACT: value = leaky(S[src]+bg).
// OMODE: 0 -> write bf16 row; 1 -> write fp32 log_softmax(+bo) row.
#define EV_DEQ (1.f / 32768.f)
template<int GACT, int OMODE>
__global__ __launch_bounds__(256) void pull_w(const int* __restrict__ off,
                                              const int* __restrict__ rec,
                                              const unsigned short* __restrict__ S,
                                              const float* __restrict__ bg,
                                              const float* __restrict__ bo,
                                              void* __restrict__ Ovp, int N) {
    int wid = (blockIdx.x * 256 + (int)threadIdx.x) >> 6;
    int lane = threadIdx.x & 63;
    if (wid >= N) return;
    int q = lane & 3, g = lane >> 2;
    int e0 = off[wid], e1 = off[wid + 1];
    float4 bv = make_float4(0, 0, 0, 0);
    if (GACT) bv = *reinterpret_cast<const float4*>(bg + q * 4);
    const uint2* Sp = reinterpret_cast<const uint2*>(S);   // 4 uint2 per row
    float ax = 0.f, ay = 0.f, az = 0.f, aw = 0.f;
    int e = e0 + g;
    for (; e + 16 < e1; e += 32) {
        unsigned r0 = (unsigned)rec[e], r1 = (unsigned)rec[e + 16];
        uint2 u0 = Sp[(size_t)(r0 >> 15) * 4 + q];
        uint2 u1 = Sp[(size_t)(r1 >> 15) * 4 + q];
        float v0 = (float)(r0 & 32767u) * EV_DEQ;
        float v1 = (float)(r1 & 32767u) * EV_DEQ;
        float s0x = bf_lo(u0.x), s0y = bf_hi(u0.x), s0z = bf_lo(u0.y), s0w = bf_hi(u0.y);
        float s1x = bf_lo(u1.x), s1y = bf_hi(u1.x), s1z = bf_lo(u1.y), s1w = bf_hi(u1.y);
        if (GACT) {
            s0x += bv.x; s0x = s0x > 0.f ? s0x : 0.01f * s0x;
            s0y += bv.y; s0y = s0y > 0.f ? s0y : 0.01f * s0y;
            s0z += bv.z; s0z = s0z > 0.f ? s0z : 0.01f * s0z;
            s0w += bv.w; s0w = s0w > 0.f ? s0w : 0.01f * s0w;
            s1x += bv.x; s1x = s1x > 0.f ? s1x : 0.01f * s1x;
            s1y += bv.y; s1y = s1y > 0.f ? s1y : 0.01f * s1y;
            s1z += bv.z; s1z = s1z > 0.f ? s1z : 0.01f * s1z;
            s1w += bv.w; s1w = s1w > 0.f ? s1w : 0.01f * s1w;
        }
        ax += v0 * s0x; ay += v0 * s0y; az += v0 * s0z; aw += v0 * s0w;
        ax += v1 * s1x; ay += v1 * s1y; az += v1 * s1z; aw += v1 * s1w;
    }
    if (e < e1) {
        unsigned r0 = (unsigned)rec[e];
        uint2 u0 = Sp[(size_t)(r0 >> 15) * 4 + q];
        float v0 = (float)(r0 & 32767u) * EV_DEQ;
        float s0x = bf_lo(u0.x), s0y = bf_hi(u0.x), s0z = bf_lo(u0.y), s0w = bf_hi(u0.y);
        if (GACT) {
            s0x += bv.x; s0x = s0x > 0.f ? s0x : 0.01f * s0x;
            s0y += bv.y; s0y = s0y > 0.f ? s0y : 0.01f * s0y;
            s0z += bv.z; s0z = s0z > 0.f ? s0z : 0.01f * s0z;
            s0w += bv.w; s0w = s0w > 0.f ? s0w : 0.01f * s0w;
        }
        ax += v0 * s0x; ay += v0 * s0y; az += v0 * s0z; aw += v0 * s0w;
    }
    // reduce across the 16 edge groups (lane bits 2..5)
#pragma unroll
    for (int m = 4; m <= 32; m <<= 1) {
        ax += __shfl_xor(ax, m);
        ay += __shfl_xor(ay, m);
        az += __shfl_xor(az, m);
        aw += __shfl_xor(aw, m);
    }
    if (OMODE == 0) {
        if (lane < 4) {
            unsigned short* O = (unsigned short*)Ovp;
            uint2 o;
            o.x = pack2bf(ax, ay);
            o.y = pack2bf(az, aw);
            reinterpret_cast<uint2*>(O + (size_t)wid * 16)[lane] = o;
        }
    } else {
        float* O = (float*)Ovp;
        float4 b3v = *reinterpret_cast<const float4*>(bo + q * 4);
        float x0 = ax + b3v.x, x1 = ay + b3v.y, x2 = az + b3v.z, x3 = aw + b3v.w;
        float m = fmaxf(fmaxf(x0, x1), fmaxf(x2, x3));
        m = fmaxf(m, __shfl_xor(m, 1));
        m = fmaxf(m, __shfl_xor(m, 2));
        float ss = __expf(x0 - m) + __expf(x1 - m) + __expf(x2 - m) + __expf(x3 - m);
        ss += __shfl_xor(ss, 1);
        ss += __shfl_xor(ss, 2);
        float lse = m + __logf(ss);
        if (lane < 4)
            *reinterpret_cast<float4*>(O + (size_t)wid * 16 + lane * 4) =
                make_float4(x0 - lse, x1 - lse, x2 - lse, x3 - lse);
    }
}

// ---------------- fused gemm2+leaky+gemm3 (bf16 in/out) -------------------
__global__ __launch_bounds__(256) void gemm23_k(const unsigned short* __restrict__ A,
                                                const float* __restrict__ W2,
                                                const float* __restrict__ b2,
                                                const float* __restrict__ W3,
                                                unsigned short* __restrict__ T3, int N) {
    int row = blockIdx.x * 256 + threadIdx.x;
    if (row >= N) return;
    float a[16];
    const uint2* Av = reinterpret_cast<const uint2*>(A + (size_t)row * 16);
#pragma unroll
    for (int qq = 0; qq < 4; ++qq) {
        uint2 v = Av[qq];
        a[4*qq+0] = bf_lo(v.x); a[4*qq+1] = bf_hi(v.x);
        a[4*qq+2] = bf_lo(v.y); a[4*qq+3] = bf_hi(v.y);
    }
    float h[64];
#pragma unroll
    for (int j = 0; j < 64; ++j) h[j] = b2[j];
#pragma unroll
    for (int k = 0; k < 16; ++k)
#pragma unroll
        for (int j = 0; j < 64; ++j)
            h[j] += a[k] * W2[(size_t)k * 64 + j];
#pragma unroll
    for (int j = 0; j < 64; ++j) h[j] = h[j] > 0.f ? h[j] : 0.01f * h[j];
    float o[16];
#pragma unroll
    for (int c = 0; c < 16; ++c) o[c] = 0.f;
#pragma unroll
    for (int j = 0; j < 64; ++j)
#pragma unroll
        for (int c = 0; c < 16; ++c)
            o[c] += h[j] * W3[(size_t)j * 16 + c];
    unsigned r[8];
#pragma unroll
    for (int i = 0; i < 8; ++i) r[i] = pack2bf(o[2*i], o[2*i+1]);
    uint4* Tv = reinterpret_cast<uint4*>(T3 + (size_t)row * 16);
    Tv[0] = make_uint4(r[0], r[1], r[2], r[3]);
    Tv[1] = make_uint4(r[4], r[5], r[6], r[7]);
}

extern "C" void kernel_launch(void* const* d_in, const int* in_sizes, int n_in,
                              void* d_out, int out_size, void* d_ws, size_t ws_size,
                              hipStream_t stream) {
    const float* x   = (const float*)d_in[0];
    const int*   src = (const int*)d_in[1];
    const int*   dst = (const int*)d_in[2];
    const float* ev  = (const float*)d_in[3];
    const float* W1  = (const float*)d_in[4];
    const float* b1  = (const float*)d_in[5];
    const float* W2  = (const float*)d_in[6];
    const float* b2  = (const float*)d_in[7];
    const float* W3  = (const float*)d_in[8];
    const float* b3  = (const float*)d_in[9];
    float* out = (float*)d_out;

    const int N = in_sizes[0] / 512;   // 100000
    const int E = in_sizes[1];         // 3200000

    // workspace layout (recA recycled as B1/B2 after sort2); bf16 tables
    unsigned short* B0 = (unsigned short*)d_ws;        // N x 16 bf16 (t1 / t3)
    int2*  recA  = (int2*)(B0 + (size_t)N * 16);       // E {src|dl<<17, ev}
    int*   recB  = (int*)(recA + E);                   // E node-sorted src<<15|ev15
    int*   C     = recB + E;                           // NBLK x NBKT
    int*   btot  = C + (size_t)NBLK * NBKT;            // NBKT
    int*   bbase = btot + NBKT;                        // NBKT+1
    int*   off   = bbase + (NBKT + 1);                 // N+1
    unsigned short* B1 = (unsigned short*)recA;        // N x 16 bf16 (a1)
    unsigned short* B2 = B1 + (size_t)N * 16;          // N x 16 bf16 (a2)

    auto blks = [](long n) { return (int)((n + 255) / 256); };
    const int ntiles = (N + 15) / 16;               // 6250 MFMA row-tiles
    const int NB_gemm = (ntiles + 3) / 4;           // 4 waves/block -> 1563
    const int pull_blocks = blks((long)N * 64);     // wave per node

    // ---- partition build (no global atomics) + MFMA gemm1 ----
    p1g_k<<<NB_gemm + NBLK, 256, 0, stream>>>(x, W1, B0, dst, C, N, E, NB_gemm);
    p2a<<<(NBKT + 15) / 16, 256, 0, stream>>>(C, btot);
    p2b<<<1, 256, 0, stream>>>(btot, bbase, E);
    p3_place<<<NBLK, 256, 0, stream>>>(src, dst, ev, C, bbase, recA, E);
    sort2_k<<<NBKT, 256, 0, stream>>>(bbase, recA, recB, off, N, E);

    // ---- layer 1 aggregate: a1 = spmm(t1) (bf16 out) ----
    pull_w<0, 0><<<pull_blocks, 256, 0, stream>>>(off, recB, B0, nullptr, nullptr, B1, N);

    // ---- layer 2 aggregate: a2 = spmm(leaky(a1+b1)) (bf16 out) ----
    pull_w<1, 0><<<pull_blocks, 256, 0, stream>>>(off, recB, B1, b1, nullptr, B2, N);

    // ---- t3 = leaky(a2@W2+b2)@W3 (bf16 in/out) ----
    gemm23_k<<<NB_gemm, 256, 0, stream>>>(B2, W2, b2, W3, B0, N);

    // ---- layer 3 aggregate + bias + log_softmax -> out (fp32) ----
    pull_w<0, 1><<<pull_blocks, 256, 0, stream>>>(off, recB, B0, nullptr, b3, out, N);
}

// Round 21
// 242.045 us; speedup vs baseline: 1.4282x; 1.0893x over previous
//
#include <hip/hip_runtime.h>
#include <cmath>

// GCN: 3 x (dense GEMM <-> pull-SpMM) + fused log_softmax.
// Build: atomic-free two-level counting partition (bucket = dst>>7) ->
// within-bucket counting sort (sort2) -> compact per-node CSR with 4-byte
// records (src 17b | ev 15b fixed-point). gemm1 = MFMA 16x16x32 bf16.
// All pull tables bf16 (3.2MB -> L2-resident). XCD-aware chunk swizzle in
// p3 (write-side line merge in per-XCD L2).
// Round-21 change: p3's edge loop manually unrolled x4 (edges e, e+256,
// e+512, e+768 per iteration). The old loop was ONE dependency chain per
// thread ({load -> ds_add_rtn ~100cy -> dependent store} x12 serial);
// BD/NBLK/write-amp changes were all neutral, pointing at atomic+store
// LATENCY as p3's bound. ILP-4 gives 4 independent chains.
// Pulls: wave-per-node, 16 groups x 4 lanes x uint2(4xbf16). No global
// atomics. Algebra: spmm(A, h@W) == spmm(A, h)@W -> aggregate in dim 16.
// Layer-1 activation recomputed inside layer-2's gather.

#define BD 128                           // dsts per bucket
#define NBKT 782                         // ceil(100000/128)
#define NBLK 1024                        // partition blocks (8 XCDs x 128)
#define SORT_CAP 6144                    // max bucket edges staged in LDS

typedef __attribute__((ext_vector_type(8))) short bf16x8;
typedef __attribute__((ext_vector_type(4))) float f32x4;

__device__ __forceinline__ short to_bf16(float f) {
    unsigned u = __float_as_uint(f);
    u += 0x8000u;                         // round-half-up
    return (short)(u >> 16);
}
__device__ __forceinline__ unsigned pack2bf(float a, float b) {
    return (unsigned)(unsigned short)to_bf16(a) |
           ((unsigned)(unsigned short)to_bf16(b) << 16);
}
__device__ __forceinline__ float bf_lo(unsigned v) { return __uint_as_float(v << 16); }
__device__ __forceinline__ float bf_hi(unsigned v) { return __uint_as_float(v & 0xFFFF0000u); }

// ---------------- fused: gemm1 MFMA (x@W1 -> t1 bf16) + bucket hist -------
__global__ __launch_bounds__(256) void p1g_k(const float* __restrict__ x,
                                             const float* __restrict__ W1,
                                             unsigned short* __restrict__ t1,
                                             const int* __restrict__ dst,
                                             int* __restrict__ C,
                                             int N, int E, int NB_gemm) {
    __shared__ __align__(16) unsigned short wlds[8192];  // 16 KB (union w/ hist)
    if ((int)blockIdx.x < NB_gemm) {
        // --- stage W1 as bf16 B-fragments: [kt][kg][col][j] (j contiguous) ---
        {
            int t = threadIdx.x;
            int kt = t >> 4, col = t & 15;
#pragma unroll
            for (int j = 0; j < 32; ++j) {
                int k = kt * 32 + j;
                float v = W1[(size_t)k * 16 + col];
                wlds[(((kt * 4 + (j >> 3)) * 16 + col) << 3) + (j & 7)] =
                    (unsigned short)to_bf16(v);
            }
        }
        __syncthreads();
        int wid = (blockIdx.x * 256 + (int)threadIdx.x) >> 6;  // global wave id
        int ntiles = (N + 15) >> 4;
        if (wid >= ntiles) return;
        int lane = threadIdx.x & 63;
        int m = lane & 15, kg = lane >> 4;
        int r = wid * 16 + m;
        int rc = r < N ? r : N - 1;                      // clamp (no OOB addr)
        const float4* Xv = reinterpret_cast<const float4*>(x + (size_t)rc * 512);
        f32x4 acc = {0.f, 0.f, 0.f, 0.f};
#pragma unroll
        for (int kt = 0; kt < 16; ++kt) {
            float4 xa = Xv[kt * 8 + kg * 2];
            float4 xb = Xv[kt * 8 + kg * 2 + 1];
            bf16x8 a;
            a[0] = to_bf16(xa.x); a[1] = to_bf16(xa.y);
            a[2] = to_bf16(xa.z); a[3] = to_bf16(xa.w);
            a[4] = to_bf16(xb.x); a[5] = to_bf16(xb.y);
            a[6] = to_bf16(xb.z); a[7] = to_bf16(xb.w);
            bf16x8 b = *reinterpret_cast<const bf16x8*>(
                &wlds[((kt * 4 + kg) * 16 + m) << 3]);
            acc = __builtin_amdgcn_mfma_f32_16x16x32_bf16(a, b, acc, 0, 0, 0);
        }
        // D: col = lane&15 (=m), row = kg*4 + i
#pragma unroll
        for (int i = 0; i < 4; ++i) {
            int ro = wid * 16 + kg * 4 + i;
            if (ro < N) t1[(size_t)ro * 16 + m] = (unsigned short)to_bf16(acc[i]);
        }
        return;
    }
    int* h = (int*)wlds;
    int k = (int)blockIdx.x - NB_gemm;
    for (int i = threadIdx.x; i < NBKT; i += 256) h[i] = 0;
    __syncthreads();
    int epb = (E + NBLK - 1) / NBLK;
    int lo = k * epb, hi = min(lo + epb, E);
    for (int e = lo + (int)threadIdx.x; e < hi; e += 256)
        atomicAdd(&h[dst[e] >> 7], 1);
    __syncthreads();
    for (int i = threadIdx.x; i < NBKT; i += 256)
        C[(size_t)k * NBKT + i] = h[i];
}

// ---------------- P2a: coalesced scan over origin blocks per bucket -------
__global__ __launch_bounds__(256) void p2a(int* __restrict__ C,
                                           int* __restrict__ btot) {
    __shared__ int s[16][17];
    int bs = threadIdx.x & 15, ki = threadIdx.x >> 4;
    int b = blockIdx.x * 16 + bs;
    bool ok = b < NBKT;
    int sum = 0;
    if (ok) {
        for (int j = 0; j < 64; ++j)
            sum += C[(size_t)(ki * 64 + j) * NBKT + b];
    }
    s[ki][bs] = sum;
    __syncthreads();
    int base = 0;
    for (int j = 0; j < ki; ++j) base += s[j][bs];
    if (ok) {
        if (ki == 15) btot[b] = base + sum;
        int run = base;
        for (int j = 0; j < 64; ++j) {
            size_t idx = (size_t)(ki * 64 + j) * NBKT + b;
            int v = C[idx];
            C[idx] = run;                 // exclusive offset
            run += v;
        }
    }
}

// ---------------- P2b: exclusive scan of bucket totals -> bucket bases ----
__global__ __launch_bounds__(256) void p2b(const int* __restrict__ btot,
                                           int* __restrict__ bbase, int E) {
    __shared__ int ps[256];
    int loc[8], sum = 0;
    int base = (int)threadIdx.x * 8;     // 2048 >= NBKT+1
#pragma unroll
    for (int j = 0; j < 8; ++j) {
        int i = base + j;
        int v = (i < NBKT) ? btot[i] : 0;
        loc[j] = sum; sum += v;
    }
    ps[threadIdx.x] = sum;
    __syncthreads();
    for (int st = 1; st < 256; st <<= 1) {
        int tv = (threadIdx.x >= (unsigned)st) ? ps[threadIdx.x - st] : 0;
        __syncthreads();
        ps[threadIdx.x] += tv;
        __syncthreads();
    }
    int prev = ps[threadIdx.x] - sum;
#pragma unroll
    for (int j = 0; j < 8; ++j) {
        int i = base + j;
        if (i <= NBKT) bbase[i] = prev + loc[j];
    }
}

// ---------------- P3: scatter bucket-sorted records (LDS cursors) ---------
// XCD swizzle: chunks 128k..128k+127 run on XCD k (write-side L2 merge).
// ILP-4: four independent {load, ds_add_rtn, store} chains per thread.
__global__ __launch_bounds__(256) void p3_place(const int* __restrict__ src,
                                                const int* __restrict__ dst,
                                                const float* __restrict__ ev,
                                                const int* __restrict__ C,
                                                const int* __restrict__ bbase,
                                                int2* __restrict__ recA, int E) {
    __shared__ int cur[NBKT];
    int bid = (int)blockIdx.x;
    int k = ((bid & 7) << 7) | (bid >> 3);   // (bid%8)*128 + bid/8
    for (int i = threadIdx.x; i < NBKT; i += 256)
        cur[i] = bbase[i] + C[(size_t)k * NBKT + i];
    __syncthreads();
    int epb = (E + NBLK - 1) / NBLK;
    int lo = k * epb, hi = min(lo + epb, E);
    int e = lo + (int)threadIdx.x;
    for (; e + 768 < hi; e += 1024) {
        int d0 = dst[e],       s0 = src[e],       v0 = __float_as_int(ev[e]);
        int d1 = dst[e + 256], s1 = src[e + 256], v1 = __float_as_int(ev[e + 256]);
        int d2 = dst[e + 512], s2 = src[e + 512], v2 = __float_as_int(ev[e + 512]);
        int d3 = dst[e + 768], s3 = src[e + 768], v3 = __float_as_int(ev[e + 768]);
        int p0 = atomicAdd(&cur[d0 >> 7], 1);
        int p1 = atomicAdd(&cur[d1 >> 7], 1);
        int p2 = atomicAdd(&cur[d2 >> 7], 1);
        int p3 = atomicAdd(&cur[d3 >> 7], 1);
        recA[p0] = make_int2(s0 | ((d0 & 127) << 17), v0);
        recA[p1] = make_int2(s1 | ((d1 & 127) << 17), v1);
        recA[p2] = make_int2(s2 | ((d2 & 127) << 17), v2);
        recA[p3] = make_int2(s3 | ((d3 & 127) << 17), v3);
    }
    for (; e < hi; e += 256) {
        int d = dst[e];
        int p = atomicAdd(&cur[d >> 7], 1);   // LDS ds_add_rtn
        recA[p] = make_int2(src[e] | ((d & 127) << 17), __float_as_int(ev[e]));
    }
}

// ---------------- sort2: within-bucket counting sort -> 4B-record CSR -----
__device__ __forceinline__ int pack_rec(int srcbits, float evf) {
    int q = (int)(evf * 32768.f + 0.5f);
    q = q > 32767 ? 32767 : q;
    return (srcbits << 15) | q;
}

__global__ __launch_bounds__(256) void sort2_k(const int* __restrict__ bbase,
                                               const int2* __restrict__ recA,
                                               int* __restrict__ recB,
                                               int* __restrict__ off,
                                               int N, int E) {
    __shared__ int2 ls[SORT_CAP];
    __shared__ int lo_[SORT_CAP];
    __shared__ int cnt[BD];
    __shared__ int cur[BD];
    __shared__ int sc[BD];
    int b = blockIdx.x;
    int e0 = bbase[b], e1 = bbase[b + 1], n = e1 - e0;
    int t = threadIdx.x;
    if (t < BD) cnt[t] = 0;
    __syncthreads();
    if (n <= SORT_CAP) {
        for (int i = t; i < n; i += 256) {
            int2 r = recA[e0 + i];
            ls[i] = r;
            atomicAdd(&cnt[(r.x >> 17) & 127], 1);
        }
        __syncthreads();
        // 128-wide Hillis-Steele inclusive scan in LDS
        if (t < BD) sc[t] = cnt[t];
        __syncthreads();
        for (int st = 1; st < BD; st <<= 1) {
            int v = (t < BD && t >= st) ? sc[t - st] : 0;
            __syncthreads();
            if (t < BD) sc[t] += v;
            __syncthreads();
        }
        if (t < BD) {
            int excl = sc[t] - cnt[t];
            cur[t] = excl;
            int node = b * BD + t;
            if (node < N) off[node] = e0 + excl;
        }
        if (t == BD && b == (int)gridDim.x - 1) off[N] = E;
        __syncthreads();
        for (int i = t; i < n; i += 256) {
            int2 r = ls[i];
            int p = atomicAdd(&cur[(r.x >> 17) & 127], 1);
            lo_[p] = pack_rec(r.x & 0x1FFFF, __int_as_float(r.y));
        }
        __syncthreads();
        for (int i = t; i < n; i += 256)
            recB[e0 + i] = lo_[i];          // coalesced
    } else {
        // exact fallback (statistically unreachable): 2-pass global
        for (int i = t; i < n; i += 256)
            atomicAdd(&cnt[(recA[e0 + i].x >> 17) & 127], 1);
        __syncthreads();
        if (t < BD) sc[t] = cnt[t];
        __syncthreads();
        for (int st = 1; st < BD; st <<= 1) {
            int v = (t < BD && t >= st) ? sc[t - st] : 0;
            __syncthreads();
            if (t < BD) sc[t] += v;
            __syncthreads();
        }
        if (t < BD) {
            int excl = sc[t] - cnt[t];
            cur[t] = excl;
            int node = b * BD + t;
            if (node < N) off[node] = e0 + excl;
        }
        if (t == BD && b == (int)gridDim.x - 1) off[N] = E;
        __syncthreads();
        for (int i = t; i < n; i += 256) {
            int2 r = recA[e0 + i];
            int p = atomicAdd(&cur[(r.x >> 17) & 127], 1);
            recB[e0 + p] = pack_rec(r.x & 0x1FFFF, __int_as_float(r.y));
        }
    }
}

// ---------------- pull: wave per node, 16 groups x 4 lanes x uint2 --------
// S = bf16 rows (16 x bf16 = 32B). GACT: value = leaky(S[src]+bg).
// OMODE: 0 -> write bf16 row; 1 -> write fp32 log_softmax(+bo) row.
#define EV_DEQ (1.f / 32768.f)
template<int GACT, int OMODE>
__global__ __launch_bounds__(256) void pull_w(const int* __restrict__ off,
                                              const int* __restrict__ rec,
                                              const unsigned short* __restrict__ S,
                                              const float* __restrict__ bg,
                                              const float* __restrict__ bo,
                                              void* __restrict__ Ovp, int N) {
    int wid = (blockIdx.x * 256 + (int)threadIdx.x) >> 6;
    int lane = threadIdx.x & 63;
    if (wid >= N) return;
    int q = lane & 3, g = lane >> 2;
    int e0 = off[wid], e1 = off[wid + 1];
    float4 bv = make_float4(0, 0, 0, 0);
    if (GACT) bv = *reinterpret_cast<const float4*>(bg + q * 4);
    const uint2* Sp = reinterpret_cast<const uint2*>(S);   // 4 uint2 per row
    float ax = 0.f, ay = 0.f, az = 0.f, aw = 0.f;
    int e = e0 + g;
    for (; e + 16 < e1; e += 32) {
        unsigned r0 = (unsigned)rec[e], r1 = (unsigned)rec[e + 16];
        uint2 u0 = Sp[(size_t)(r0 >> 15) * 4 + q];
        uint2 u1 = Sp[(size_t)(r1 >> 15) * 4 + q];
        float v0 = (float)(r0 & 32767u) * EV_DEQ;
        float v1 = (float)(r1 & 32767u) * EV_DEQ;
        float s0x = bf_lo(u0.x), s0y = bf_hi(u0.x), s0z = bf_lo(u0.y), s0w = bf_hi(u0.y);
        float s1x = bf_lo(u1.x), s1y = bf_hi(u1.x), s1z = bf_lo(u1.y), s1w = bf_hi(u1.y);
        if (GACT) {
            s0x += bv.x; s0x = s0x > 0.f ? s0x : 0.01f * s0x;
            s0y += bv.y; s0y = s0y > 0.f ? s0y : 0.01f * s0y;
            s0z += bv.z; s0z = s0z > 0.f ? s0z : 0.01f * s0z;
            s0w += bv.w; s0w = s0w > 0.f ? s0w : 0.01f * s0w;
            s1x += bv.x; s1x = s1x > 0.f ? s1x : 0.01f * s1x;
            s1y += bv.y; s1y = s1y > 0.f ? s1y : 0.01f * s1y;
            s1z += bv.z; s1z = s1z > 0.f ? s1z : 0.01f * s1z;
            s1w += bv.w; s1w = s1w > 0.f ? s1w : 0.01f * s1w;
        }
        ax += v0 * s0x; ay += v0 * s0y; az += v0 * s0z; aw += v0 * s0w;
        ax += v1 * s1x; ay += v1 * s1y; az += v1 * s1z; aw += v1 * s1w;
    }
    if (e < e1) {
        unsigned r0 = (unsigned)rec[e];
        uint2 u0 = Sp[(size_t)(r0 >> 15) * 4 + q];
        float v0 = (float)(r0 & 32767u) * EV_DEQ;
        float s0x = bf_lo(u0.x), s0y = bf_hi(u0.x), s0z = bf_lo(u0.y), s0w = bf_hi(u0.y);
        if (GACT) {
            s0x += bv.x; s0x = s0x > 0.f ? s0x : 0.01f * s0x;
            s0y += bv.y; s0y = s0y > 0.f ? s0y : 0.01f * s0y;
            s0z += bv.z; s0z = s0z > 0.f ? s0z : 0.01f * s0z;
            s0w += bv.w; s0w = s0w > 0.f ? s0w : 0.01f * s0w;
        }
        ax += v0 * s0x; ay += v0 * s0y; az += v0 * s0z; aw += v0 * s0w;
    }
    // reduce across the 16 edge groups (lane bits 2..5)
#pragma unroll
    for (int m = 4; m <= 32; m <<= 1) {
        ax += __shfl_xor(ax, m);
        ay += __shfl_xor(ay, m);
        az += __shfl_xor(az, m);
        aw += __shfl_xor(aw, m);
    }
    if (OMODE == 0) {
        if (lane < 4) {
            unsigned short* O = (unsigned short*)Ovp;
            uint2 o;
            o.x = pack2bf(ax, ay);
            o.y = pack2bf(az, aw);
            reinterpret_cast<uint2*>(O + (size_t)wid * 16)[lane] = o;
        }
    } else {
        float* O = (float*)Ovp;
        float4 b3v = *reinterpret_cast<const float4*>(bo + q * 4);
        float x0 = ax + b3v.x, x1 = ay + b3v.y, x2 = az + b3v.z, x3 = aw + b3v.w;
        float m = fmaxf(fmaxf(x0, x1), fmaxf(x2, x3));
        m = fmaxf(m, __shfl_xor(m, 1));
        m = fmaxf(m, __shfl_xor(m, 2));
        float ss = __expf(x0 - m) + __expf(x1 - m) + __expf(x2 - m) + __expf(x3 - m);
        ss += __shfl_xor(ss, 1);
        ss += __shfl_xor(ss, 2);
        float lse = m + __logf(ss);
        if (lane < 4)
            *reinterpret_cast<float4*>(O + (size_t)wid * 16 + lane * 4) =
                make_float4(x0 - lse, x1 - lse, x2 - lse, x3 - lse);
    }
}

// ---------------- fused gemm2+leaky+gemm3 (bf16 in/out) -------------------
__global__ __launch_bounds__(256) void gemm23_k(const unsigned short* __restrict__ A,
                                                const float* __restrict__ W2,
                                                const float* __restrict__ b2,
                                                const float* __restrict__ W3,
                                                unsigned short* __restrict__ T3, int N) {
    int row = blockIdx.x * 256 + threadIdx.x;
    if (row >= N) return;
    float a[16];
    const uint2* Av = reinterpret_cast<const uint2*>(A + (size_t)row * 16);
#pragma unroll
    for (int qq = 0; qq < 4; ++qq) {
        uint2 v = Av[qq];
        a[4*qq+0] = bf_lo(v.x); a[4*qq+1] = bf_hi(v.x);
        a[4*qq+2] = bf_lo(v.y); a[4*qq+3] = bf_hi(v.y);
    }
    float h[64];
#pragma unroll
    for (int j = 0; j < 64; ++j) h[j] = b2[j];
#pragma unroll
    for (int k = 0; k < 16; ++k)
#pragma unroll
        for (int j = 0; j < 64; ++j)
            h[j] += a[k] * W2[(size_t)k * 64 + j];
#pragma unroll
    for (int j = 0; j < 64; ++j) h[j] = h[j] > 0.f ? h[j] : 0.01f * h[j];
    float o[16];
#pragma unroll
    for (int c = 0; c < 16; ++c) o[c] = 0.f;
#pragma unroll
    for (int j = 0; j < 64; ++j)
#pragma unroll
        for (int c = 0; c < 16; ++c)
            o[c] += h[j] * W3[(size_t)j * 16 + c];
    unsigned r[8];
#pragma unroll
    for (int i = 0; i < 8; ++i) r[i] = pack2bf(o[2*i], o[2*i+1]);
    uint4* Tv = reinterpret_cast<uint4*>(T3 + (size_t)row * 16);
    Tv[0] = make_uint4(r[0], r[1], r[2], r[3]);
    Tv[1] = make_uint4(r[4], r[5], r[6], r[7]);
}

extern "C" void kernel_launch(void* const* d_in, const int* in_sizes, int n_in,
                              void* d_out, int out_size, void* d_ws, size_t ws_size,
                              hipStream_t stream) {
    const float* x   = (const float*)d_in[0];
    const int*   src = (const int*)d_in[1];
    const int*   dst = (const int*)d_in[2];
    const float* ev  = (const float*)d_in[3];
    const float* W1  = (const float*)d_in[4];
    const float* b1  = (const float*)d_in[5];
    const float* W2  = (const float*)d_in[6];
    const float* b2  = (const float*)d_in[7];
    const float* W3  = (const float*)d_in[8];
    const float* b3  = (const float*)d_in[9];
    float* out = (float*)d_out;

    const int N = in_sizes[0] / 512;   // 100000
    const int E = in_sizes[1];         // 3200000

    // workspace layout (recA recycled as B1/B2 after sort2); bf16 tables
    unsigned short* B0 = (unsigned short*)d_ws;        // N x 16 bf16 (t1 / t3)
    int2*  recA  = (int2*)(B0 + (size_t)N * 16);       // E {src|dl<<17, ev}
    int*   recB  = (int*)(recA + E);                   // E node-sorted src<<15|ev15
    int*   C     = recB + E;                           // NBLK x NBKT
    int*   btot  = C + (size_t)NBLK * NBKT;            // NBKT
    int*   bbase = btot + NBKT;                        // NBKT+1
    int*   off   = bbase + (NBKT + 1);                 // N+1
    unsigned short* B1 = (unsigned short*)recA;        // N x 16 bf16 (a1)
    unsigned short* B2 = B1 + (size_t)N * 16;          // N x 16 bf16 (a2)

    auto blks = [](long n) { return (int)((n + 255) / 256); };
    const int ntiles = (N + 15) / 16;               // 6250 MFMA row-tiles
    const int NB_gemm = (ntiles + 3) / 4;           // 4 waves/block -> 1563
    const int pull_blocks = blks((long)N * 64);     // wave per node

    // ---- partition build (no global atomics) + MFMA gemm1 ----
    p1g_k<<<NB_gemm + NBLK, 256, 0, stream>>>(x, W1, B0, dst, C, N, E, NB_gemm);
    p2a<<<(NBKT + 15) / 16, 256, 0, stream>>>(C, btot);
    p2b<<<1, 256, 0, stream>>>(btot, bbase, E);
    p3_place<<<NBLK, 256, 0, stream>>>(src, dst, ev, C, bbase, recA, E);
    sort2_k<<<NBKT, 256, 0, stream>>>(bbase, recA, recB, off, N, E);

    // ---- layer 1 aggregate: a1 = spmm(t1) (bf16 out) ----
    pull_w<0, 0><<<pull_blocks, 256, 0, stream>>>(off, recB, B0, nullptr, nullptr, B1, N);

    // ---- layer 2 aggregate: a2 = spmm(leaky(a1+b1)) (bf16 out) ----
    pull_w<1, 0><<<pull_blocks, 256, 0, stream>>>(off, recB, B1, b1, nullptr, B2, N);

    // ---- t3 = leaky(a2@W2+b2)@W3 (bf16 in/out) ----
    gemm23_k<<<NB_gemm, 256, 0, stream>>>(B2, W2, b2, W3, B0, N);

    // ---- layer 3 aggregate + bias + log_softmax -> out (fp32) ----
    pull_w<0, 1><<<pull_blocks, 256, 0, stream>>>(off, recB, B0, nullptr, b3, out, N);
}

// Round 22
// 240.504 us; speedup vs baseline: 1.4373x; 1.0064x over previous
//
#include <hip/hip_runtime.h>
#include <cmath>

// GCN: 3 x (dense GEMM <-> pull-SpMM) + fused log_softmax.
// Build: atomic-free two-level counting partition (bucket = dst>>7) ->
// within-bucket counting sort (sort2) -> compact per-node CSR with 4-byte
// records (src 17b | ev 15b fixed-point). gemm1 = MFMA 16x16x32 bf16.
// All pull tables bf16 (3.2MB -> L2-resident). XCD-aware chunk swizzle in
// p3 (write-side L2 line merge). p3 edge loop ILP-4 (round-21: -22us,
// confirmed the ds_add_rtn+store latency-chain diagnosis).
// Round-22 change: same ILP-4 applied to sort2's placement loop -- the
// last remaining returning-atomic serial chain ({LDS read -> ds_add_rtn
// -> dependent LDS write} x16 per thread).
// Pulls: wave-per-node, 16 groups x 4 lanes x uint2(4xbf16). No global
// atomics. Algebra: spmm(A, h@W) == spmm(A, h)@W -> aggregate in dim 16.
// Layer-1 activation recomputed inside layer-2's gather.

#define BD 128                           // dsts per bucket
#define NBKT 782                         // ceil(100000/128)
#define NBLK 1024                        // partition blocks (8 XCDs x 128)
#define SORT_CAP 6144                    // max bucket edges staged in LDS

typedef __attribute__((ext_vector_type(8))) short bf16x8;
typedef __attribute__((ext_vector_type(4))) float f32x4;

__device__ __forceinline__ short to_bf16(float f) {
    unsigned u = __float_as_uint(f);
    u += 0x8000u;                         // round-half-up
    return (short)(u >> 16);
}
__device__ __forceinline__ unsigned pack2bf(float a, float b) {
    return (unsigned)(unsigned short)to_bf16(a) |
           ((unsigned)(unsigned short)to_bf16(b) << 16);
}
__device__ __forceinline__ float bf_lo(unsigned v) { return __uint_as_float(v << 16); }
__device__ __forceinline__ float bf_hi(unsigned v) { return __uint_as_float(v & 0xFFFF0000u); }

// ---------------- fused: gemm1 MFMA (x@W1 -> t1 bf16) + bucket hist -------
__global__ __launch_bounds__(256) void p1g_k(const float* __restrict__ x,
                                             const float* __restrict__ W1,
                                             unsigned short* __restrict__ t1,
                                             const int* __restrict__ dst,
                                             int* __restrict__ C,
                                             int N, int E, int NB_gemm) {
    __shared__ __align__(16) unsigned short wlds[8192];  // 16 KB (union w/ hist)
    if ((int)blockIdx.x < NB_gemm) {
        // --- stage W1 as bf16 B-fragments: [kt][kg][col][j] (j contiguous) ---
        {
            int t = threadIdx.x;
            int kt = t >> 4, col = t & 15;
#pragma unroll
            for (int j = 0; j < 32; ++j) {
                int k = kt * 32 + j;
                float v = W1[(size_t)k * 16 + col];
                wlds[(((kt * 4 + (j >> 3)) * 16 + col) << 3) + (j & 7)] =
                    (unsigned short)to_bf16(v);
            }
        }
        __syncthreads();
        int wid = (blockIdx.x * 256 + (int)threadIdx.x) >> 6;  // global wave id
        int ntiles = (N + 15) >> 4;
        if (wid >= ntiles) return;
        int lane = threadIdx.x & 63;
        int m = lane & 15, kg = lane >> 4;
        int r = wid * 16 + m;
        int rc = r < N ? r : N - 1;                      // clamp (no OOB addr)
        const float4* Xv = reinterpret_cast<const float4*>(x + (size_t)rc * 512);
        f32x4 acc = {0.f, 0.f, 0.f, 0.f};
#pragma unroll
        for (int kt = 0; kt < 16; ++kt) {
            float4 xa = Xv[kt * 8 + kg * 2];
            float4 xb = Xv[kt * 8 + kg * 2 + 1];
            bf16x8 a;
            a[0] = to_bf16(xa.x); a[1] = to_bf16(xa.y);
            a[2] = to_bf16(xa.z); a[3] = to_bf16(xa.w);
            a[4] = to_bf16(xb.x); a[5] = to_bf16(xb.y);
            a[6] = to_bf16(xb.z); a[7] = to_bf16(xb.w);
            bf16x8 b = *reinterpret_cast<const bf16x8*>(
                &wlds[((kt * 4 + kg) * 16 + m) << 3]);
            acc = __builtin_amdgcn_mfma_f32_16x16x32_bf16(a, b, acc, 0, 0, 0);
        }
        // D: col = lane&15 (=m), row = kg*4 + i
#pragma unroll
        for (int i = 0; i < 4; ++i) {
            int ro = wid * 16 + kg * 4 + i;
            if (ro < N) t1[(size_t)ro * 16 + m] = (unsigned short)to_bf16(acc[i]);
        }
        return;
    }
    int* h = (int*)wlds;
    int k = (int)blockIdx.x - NB_gemm;
    for (int i = threadIdx.x; i < NBKT; i += 256) h[i] = 0;
    __syncthreads();
    int epb = (E + NBLK - 1) / NBLK;
    int lo = k * epb, hi = min(lo + epb, E);
    for (int e = lo + (int)threadIdx.x; e < hi; e += 256)
        atomicAdd(&h[dst[e] >> 7], 1);
    __syncthreads();
    for (int i = threadIdx.x; i < NBKT; i += 256)
        C[(size_t)k * NBKT + i] = h[i];
}

// ---------------- P2a: coalesced scan over origin blocks per bucket -------
__global__ __launch_bounds__(256) void p2a(int* __restrict__ C,
                                           int* __restrict__ btot) {
    __shared__ int s[16][17];
    int bs = threadIdx.x & 15, ki = threadIdx.x >> 4;
    int b = blockIdx.x * 16 + bs;
    bool ok = b < NBKT;
    int sum = 0;
    if (ok) {
        for (int j = 0; j < 64; ++j)
            sum += C[(size_t)(ki * 64 + j) * NBKT + b];
    }
    s[ki][bs] = sum;
    __syncthreads();
    int base = 0;
    for (int j = 0; j < ki; ++j) base += s[j][bs];
    if (ok) {
        if (ki == 15) btot[b] = base + sum;
        int run = base;
        for (int j = 0; j < 64; ++j) {
            size_t idx = (size_t)(ki * 64 + j) * NBKT + b;
            int v = C[idx];
            C[idx] = run;                 // exclusive offset
            run += v;
        }
    }
}

// ---------------- P2b: exclusive scan of bucket totals -> bucket bases ----
__global__ __launch_bounds__(256) void p2b(const int* __restrict__ btot,
                                           int* __restrict__ bbase, int E) {
    __shared__ int ps[256];
    int loc[8], sum = 0;
    int base = (int)threadIdx.x * 8;     // 2048 >= NBKT+1
#pragma unroll
    for (int j = 0; j < 8; ++j) {
        int i = base + j;
        int v = (i < NBKT) ? btot[i] : 0;
        loc[j] = sum; sum += v;
    }
    ps[threadIdx.x] = sum;
    __syncthreads();
    for (int st = 1; st < 256; st <<= 1) {
        int tv = (threadIdx.x >= (unsigned)st) ? ps[threadIdx.x - st] : 0;
        __syncthreads();
        ps[threadIdx.x] += tv;
        __syncthreads();
    }
    int prev = ps[threadIdx.x] - sum;
#pragma unroll
    for (int j = 0; j < 8; ++j) {
        int i = base + j;
        if (i <= NBKT) bbase[i] = prev + loc[j];
    }
}

// ---------------- P3: scatter bucket-sorted records (LDS cursors) ---------
// XCD swizzle: chunks 128k..128k+127 run on XCD k (write-side L2 merge).
// ILP-4: four independent {load, ds_add_rtn, store} chains per thread.
__global__ __launch_bounds__(256) void p3_place(const int* __restrict__ src,
                                                const int* __restrict__ dst,
                                                const float* __restrict__ ev,
                                                const int* __restrict__ C,
                                                const int* __restrict__ bbase,
                                                int2* __restrict__ recA, int E) {
    __shared__ int cur[NBKT];
    int bid = (int)blockIdx.x;
    int k = ((bid & 7) << 7) | (bid >> 3);   // (bid%8)*128 + bid/8
    for (int i = threadIdx.x; i < NBKT; i += 256)
        cur[i] = bbase[i] + C[(size_t)k * NBKT + i];
    __syncthreads();
    int epb = (E + NBLK - 1) / NBLK;
    int lo = k * epb, hi = min(lo + epb, E);
    int e = lo + (int)threadIdx.x;
    for (; e + 768 < hi; e += 1024) {
        int d0 = dst[e],       s0 = src[e],       v0 = __float_as_int(ev[e]);
        int d1 = dst[e + 256], s1 = src[e + 256], v1 = __float_as_int(ev[e + 256]);
        int d2 = dst[e + 512], s2 = src[e + 512], v2 = __float_as_int(ev[e + 512]);
        int d3 = dst[e + 768], s3 = src[e + 768], v3 = __float_as_int(ev[e + 768]);
        int p0 = atomicAdd(&cur[d0 >> 7], 1);
        int p1 = atomicAdd(&cur[d1 >> 7], 1);
        int p2 = atomicAdd(&cur[d2 >> 7], 1);
        int p3 = atomicAdd(&cur[d3 >> 7], 1);
        recA[p0] = make_int2(s0 | ((d0 & 127) << 17), v0);
        recA[p1] = make_int2(s1 | ((d1 & 127) << 17), v1);
        recA[p2] = make_int2(s2 | ((d2 & 127) << 17), v2);
        recA[p3] = make_int2(s3 | ((d3 & 127) << 17), v3);
    }
    for (; e < hi; e += 256) {
        int d = dst[e];
        int p = atomicAdd(&cur[d >> 7], 1);   // LDS ds_add_rtn
        recA[p] = make_int2(src[e] | ((d & 127) << 17), __float_as_int(ev[e]));
    }
}

// ---------------- sort2: within-bucket counting sort -> 4B-record CSR -----
__device__ __forceinline__ int pack_rec(int srcbits, float evf) {
    int q = (int)(evf * 32768.f + 0.5f);
    q = q > 32767 ? 32767 : q;
    return (srcbits << 15) | q;
}

__global__ __launch_bounds__(256) void sort2_k(const int* __restrict__ bbase,
                                               const int2* __restrict__ recA,
                                               int* __restrict__ recB,
                                               int* __restrict__ off,
                                               int N, int E) {
    __shared__ int2 ls[SORT_CAP];
    __shared__ int lo_[SORT_CAP];
    __shared__ int cnt[BD];
    __shared__ int cur[BD];
    __shared__ int sc[BD];
    int b = blockIdx.x;
    int e0 = bbase[b], e1 = bbase[b + 1], n = e1 - e0;
    int t = threadIdx.x;
    if (t < BD) cnt[t] = 0;
    __syncthreads();
    if (n <= SORT_CAP) {
        for (int i = t; i < n; i += 256) {
            int2 r = recA[e0 + i];
            ls[i] = r;
            atomicAdd(&cnt[(r.x >> 17) & 127], 1);   // non-rtn: pipelined
        }
        __syncthreads();
        // 128-wide Hillis-Steele inclusive scan in LDS
        if (t < BD) sc[t] = cnt[t];
        __syncthreads();
        for (int st = 1; st < BD; st <<= 1) {
            int v = (t < BD && t >= st) ? sc[t - st] : 0;
            __syncthreads();
            if (t < BD) sc[t] += v;
            __syncthreads();
        }
        if (t < BD) {
            int excl = sc[t] - cnt[t];
            cur[t] = excl;
            int node = b * BD + t;
            if (node < N) off[node] = e0 + excl;
        }
        if (t == BD && b == (int)gridDim.x - 1) off[N] = E;
        __syncthreads();
        // ---- placement: ILP-4 (4 independent ds_add_rtn chains) ----
        int i = t;
        for (; i + 768 < n; i += 1024) {
            int2 r0 = ls[i];
            int2 r1 = ls[i + 256];
            int2 r2 = ls[i + 512];
            int2 r3 = ls[i + 768];
            int p0 = atomicAdd(&cur[(r0.x >> 17) & 127], 1);
            int p1 = atomicAdd(&cur[(r1.x >> 17) & 127], 1);
            int p2 = atomicAdd(&cur[(r2.x >> 17) & 127], 1);
            int p3 = atomicAdd(&cur[(r3.x >> 17) & 127], 1);
            lo_[p0] = pack_rec(r0.x & 0x1FFFF, __int_as_float(r0.y));
            lo_[p1] = pack_rec(r1.x & 0x1FFFF, __int_as_float(r1.y));
            lo_[p2] = pack_rec(r2.x & 0x1FFFF, __int_as_float(r2.y));
            lo_[p3] = pack_rec(r3.x & 0x1FFFF, __int_as_float(r3.y));
        }
        for (; i < n; i += 256) {
            int2 r = ls[i];
            int p = atomicAdd(&cur[(r.x >> 17) & 127], 1);
            lo_[p] = pack_rec(r.x & 0x1FFFF, __int_as_float(r.y));
        }
        __syncthreads();
        for (int i2 = t; i2 < n; i2 += 256)
            recB[e0 + i2] = lo_[i2];          // coalesced
    } else {
        // exact fallback (statistically unreachable): 2-pass global
        for (int i = t; i < n; i += 256)
            atomicAdd(&cnt[(recA[e0 + i].x >> 17) & 127], 1);
        __syncthreads();
        if (t < BD) sc[t] = cnt[t];
        __syncthreads();
        for (int st = 1; st < BD; st <<= 1) {
            int v = (t < BD && t >= st) ? sc[t - st] : 0;
            __syncthreads();
            if (t < BD) sc[t] += v;
            __syncthreads();
        }
        if (t < BD) {
            int excl = sc[t] - cnt[t];
            cur[t] = excl;
            int node = b * BD + t;
            if (node < N) off[node] = e0 + excl;
        }
        if (t == BD && b == (int)gridDim.x - 1) off[N] = E;
        __syncthreads();
        for (int i = t; i < n; i += 256) {
            int2 r = recA[e0 + i];
            int p = atomicAdd(&cur[(r.x >> 17) & 127], 1);
            recB[e0 + p] = pack_rec(r.x & 0x1FFFF, __int_as_float(r.y));
        }
    }
}

// ---------------- pull: wave per node, 16 groups x 4 lanes x uint2 --------
// S = bf16 rows (16 x bf16 = 32B). GACT: value = leaky(S[src]+bg).
// OMODE: 0 -> write bf16 row; 1 -> write fp32 log_softmax(+bo) row.
#define EV_DEQ (1.f / 32768.f)
template<int GACT, int OMODE>
__global__ __launch_bounds__(256) void pull_w(const int* __restrict__ off,
                                              const int* __restrict__ rec,
                                              const unsigned short* __restrict__ S,
                                              const float* __restrict__ bg,
                                              const float* __restrict__ bo,
                                              void* __restrict__ Ovp, int N) {
    int wid = (blockIdx.x * 256 + (int)threadIdx.x) >> 6;
    int lane = threadIdx.x & 63;
    if (wid >= N) return;
    int q = lane & 3, g = lane >> 2;
    int e0 = off[wid], e1 = off[wid + 1];
    float4 bv = make_float4(0, 0, 0, 0);
    if (GACT) bv = *reinterpret_cast<const float4*>(bg + q * 4);
    const uint2* Sp = reinterpret_cast<const uint2*>(S);   // 4 uint2 per row
    float ax = 0.f, ay = 0.f, az = 0.f, aw = 0.f;
    int e = e0 + g;
    for (; e + 16 < e1; e += 32) {
        unsigned r0 = (unsigned)rec[e], r1 = (unsigned)rec[e + 16];
        uint2 u0 = Sp[(size_t)(r0 >> 15) * 4 + q];
        uint2 u1 = Sp[(size_t)(r1 >> 15) * 4 + q];
        float v0 = (float)(r0 & 32767u) * EV_DEQ;
        float v1 = (float)(r1 & 32767u) * EV_DEQ;
        float s0x = bf_lo(u0.x), s0y = bf_hi(u0.x), s0z = bf_lo(u0.y), s0w = bf_hi(u0.y);
        float s1x = bf_lo(u1.x), s1y = bf_hi(u1.x), s1z = bf_lo(u1.y), s1w = bf_hi(u1.y);
        if (GACT) {
            s0x += bv.x; s0x = s0x > 0.f ? s0x : 0.01f * s0x;
            s0y += bv.y; s0y = s0y > 0.f ? s0y : 0.01f * s0y;
            s0z += bv.z; s0z = s0z > 0.f ? s0z : 0.01f * s0z;
            s0w += bv.w; s0w = s0w > 0.f ? s0w : 0.01f * s0w;
            s1x += bv.x; s1x = s1x > 0.f ? s1x : 0.01f * s1x;
            s1y += bv.y; s1y = s1y > 0.f ? s1y : 0.01f * s1y;
            s1z += bv.z; s1z = s1z > 0.f ? s1z : 0.01f * s1z;
            s1w += bv.w; s1w = s1w > 0.f ? s1w : 0.01f * s1w;
        }
        ax += v0 * s0x; ay += v0 * s0y; az += v0 * s0z; aw += v0 * s0w;
        ax += v1 * s1x; ay += v1 * s1y; az += v1 * s1z; aw += v1 * s1w;
    }
    if (e < e1) {
        unsigned r0 = (unsigned)rec[e];
        uint2 u0 = Sp[(size_t)(r0 >> 15) * 4 + q];
        float v0 = (float)(r0 & 32767u) * EV_DEQ;
        float s0x = bf_lo(u0.x), s0y = bf_hi(u0.x), s0z = bf_lo(u0.y), s0w = bf_hi(u0.y);
        if (GACT) {
            s0x += bv.x; s0x = s0x > 0.f ? s0x : 0.01f * s0x;
            s0y += bv.y; s0y = s0y > 0.f ? s0y : 0.01f * s0y;
            s0z += bv.z; s0z = s0z > 0.f ? s0z : 0.01f * s0z;
            s0w += bv.w; s0w = s0w > 0.f ? s0w : 0.01f * s0w;
        }
        ax += v0 * s0x; ay += v0 * s0y; az += v0 * s0z; aw += v0 * s0w;
    }
    // reduce across the 16 edge groups (lane bits 2..5)
#pragma unroll
    for (int m = 4; m <= 32; m <<= 1) {
        ax += __shfl_xor(ax, m);
        ay += __shfl_xor(ay, m);
        az += __shfl_xor(az, m);
        aw += __shfl_xor(aw, m);
    }
    if (OMODE == 0) {
        if (lane < 4) {
            unsigned short* O = (unsigned short*)Ovp;
            uint2 o;
            o.x = pack2bf(ax, ay);
            o.y = pack2bf(az, aw);
            reinterpret_cast<uint2*>(O + (size_t)wid * 16)[lane] = o;
        }
    } else {
        float* O = (float*)Ovp;
        float4 b3v = *reinterpret_cast<const float4*>(bo + q * 4);
        float x0 = ax + b3v.x, x1 = ay + b3v.y, x2 = az + b3v.z, x3 = aw + b3v.w;
        float m = fmaxf(fmaxf(x0, x1), fmaxf(x2, x3));
        m = fmaxf(m, __shfl_xor(m, 1));
        m = fmaxf(m, __shfl_xor(m, 2));
        float ss = __expf(x0 - m) + __expf(x1 - m) + __expf(x2 - m) + __expf(x3 - m);
        ss += __shfl_xor(ss, 1);
        ss += __shfl_xor(ss, 2);
        float lse = m + __logf(ss);
        if (lane < 4)
            *reinterpret_cast<float4*>(O + (size_t)wid * 16 + lane * 4) =
                make_float4(x0 - lse, x1 - lse, x2 - lse, x3 - lse);
    }
}

// ---------------- fused gemm2+leaky+gemm3 (bf16 in/out) -------------------
__global__ __launch_bounds__(256) void gemm23_k(const unsigned short* __restrict__ A,
                                                const float* __restrict__ W2,
                                                const float* __restrict__ b2,
                                                const float* __restrict__ W3,
                                                unsigned short* __restrict__ T3, int N) {
    int row = blockIdx.x * 256 + threadIdx.x;
    if (row >= N) return;
    float a[16];
    const uint2* Av = reinterpret_cast<const uint2*>(A + (size_t)row * 16);
#pragma unroll
    for (int qq = 0; qq < 4; ++qq) {
        uint2 v = Av[qq];
        a[4*qq+0] = bf_lo(v.x); a[4*qq+1] = bf_hi(v.x);
        a[4*qq+2] = bf_lo(v.y); a[4*qq+3] = bf_hi(v.y);
    }
    float h[64];
#pragma unroll
    for (int j = 0; j < 64; ++j) h[j] = b2[j];
#pragma unroll
    for (int k = 0; k < 16; ++k)
#pragma unroll
        for (int j = 0; j < 64; ++j)
            h[j] += a[k] * W2[(size_t)k * 64 + j];
#pragma unroll
    for (int j = 0; j < 64; ++j) h[j] = h[j] > 0.f ? h[j] : 0.01f * h[j];
    float o[16];
#pragma unroll
    for (int c = 0; c < 16; ++c) o[c] = 0.f;
#pragma unroll
    for (int j = 0; j < 64; ++j)
#pragma unroll
        for (int c = 0; c < 16; ++c)
            o[c] += h[j] * W3[(size_t)j * 16 + c];
    unsigned r[8];
#pragma unroll
    for (int i = 0; i < 8; ++i) r[i] = pack2bf(o[2*i], o[2*i+1]);
    uint4* Tv = reinterpret_cast<uint4*>(T3 + (size_t)row * 16);
    Tv[0] = make_uint4(r[0], r[1], r[2], r[3]);
    Tv[1] = make_uint4(r[4], r[5], r[6], r[7]);
}

extern "C" void kernel_launch(void* const* d_in, const int* in_sizes, int n_in,
                              void* d_out, int out_size, void* d_ws, size_t ws_size,
                              hipStream_t stream) {
    const float* x   = (const float*)d_in[0];
    const int*   src = (const int*)d_in[1];
    const int*   dst = (const int*)d_in[2];
    const float* ev  = (const float*)d_in[3];
    const float* W1  = (const float*)d_in[4];
    const float* b1  = (const float*)d_in[5];
    const float* W2  = (const float*)d_in[6];
    const float* b2  = (const float*)d_in[7];
    const float* W3  = (const float*)d_in[8];
    const float* b3  = (const float*)d_in[9];
    float* out = (float*)d_out;

    const int N = in_sizes[0] / 512;   // 100000
    const int E = in_sizes[1];         // 3200000

    // workspace layout (recA recycled as B1/B2 after sort2); bf16 tables
    unsigned short* B0 = (unsigned short*)d_ws;        // N x 16 bf16 (t1 / t3)
    int2*  recA  = (int2*)(B0 + (size_t)N * 16);       // E {src|dl<<17, ev}
    int*   recB  = (int*)(recA + E);                   // E node-sorted src<<15|ev15
    int*   C     = recB + E;                           // NBLK x NBKT
    int*   btot  = C + (size_t)NBLK * NBKT;            // NBKT
    int*   bbase = btot + NBKT;                        // NBKT+1
    int*   off   = bbase + (NBKT + 1);                 // N+1
    unsigned short* B1 = (unsigned short*)recA;        // N x 16 bf16 (a1)
    unsigned short* B2 = B1 + (size_t)N * 16;          // N x 16 bf16 (a2)

    auto blks = [](long n) { return (int)((n + 255) / 256); };
    const int ntiles = (N + 15) / 16;               // 6250 MFMA row-tiles
    const int NB_gemm = (ntiles + 3) / 4;           // 4 waves/block -> 1563
    const int pull_blocks = blks((long)N * 64);     // wave per node

    // ---- partition build (no global atomics) + MFMA gemm1 ----
    p1g_k<<<NB_gemm + NBLK, 256, 0, stream>>>(x, W1, B0, dst, C, N, E, NB_gemm);
    p2a<<<(NBKT + 15) / 16, 256, 0, stream>>>(C, btot);
    p2b<<<1, 256, 0, stream>>>(btot, bbase, E);
    p3_place<<<NBLK, 256, 0, stream>>>(src, dst, ev, C, bbase, recA, E);
    sort2_k<<<NBKT, 256, 0, stream>>>(bbase, recA, recB, off, N, E);

    // ---- layer 1 aggregate: a1 = spmm(t1) (bf16 out) ----
    pull_w<0, 0><<<pull_blocks, 256, 0, stream>>>(off, recB, B0, nullptr, nullptr, B1, N);

    // ---- layer 2 aggregate: a2 = spmm(leaky(a1+b1)) (bf16 out) ----
    pull_w<1, 0><<<pull_blocks, 256, 0, stream>>>(off, recB, B1, b1, nullptr, B2, N);

    // ---- t3 = leaky(a2@W2+b2)@W3 (bf16 in/out) ----
    gemm23_k<<<NB_gemm, 256, 0, stream>>>(B2, W2, b2, W3, B0, N);

    // ---- layer 3 aggregate + bias + log_softmax -> out (fp32) ----
    pull_w<0, 1><<<pull_blocks, 256, 0, stream>>>(off, recB, B0, nullptr, b3, out, N);
}